// Round 6
// baseline (662.277 us; speedup 1.0000x reference)
//
#include <hip/hip_runtime.h>
#include <hip/hip_cooperative_groups.h>

#define D 128
#define SCAN_B 256
#define NT 32            // nodes per fused_ag block
#define HPAD 132         // padded LDS row (floats) — breaks stride-128 bank alias

typedef short bf16x8 __attribute__((ext_vector_type(8)));
typedef float f32x4 __attribute__((ext_vector_type(4)));

static __device__ __forceinline__ unsigned short f2bf(float f) {
  union { float f; unsigned u; } v; v.f = f;
  return (unsigned short)((v.u + 0x7FFF + ((v.u >> 16) & 1)) >> 16);   // RNE
}
static __device__ __forceinline__ float bf2f(unsigned short h) {
  union { unsigned u; float f; } v; v.u = ((unsigned)h) << 16;
  return v.f;
}
static __device__ __forceinline__ float bflo(unsigned u) {
  union { unsigned u; float f; } v; v.u = u << 16; return v.f;
}
static __device__ __forceinline__ float bfhi(unsigned u) {
  union { unsigned u; float f; } v; v.u = u & 0xFFFF0000u; return v.f;
}

// ---------------------------------------------------------------------------
// mid_coop: ONE cooperative dispatch replacing prep+hist+scan1+scan3+fill.
//  phase0: Wb swizzle + rel_out GEMV + zero offs + xb=bf16(x)   (independent)
//  gsync
//  phase1: dst histogram (atomics into zeroed offs)
//  gsync
//  phase2: exclusive scan of offs (chunk sums -> block-0 scan -> apply)
//  gsync x3
//  phase3: fill CSR-ordered packed meta; offs becomes bucket-end cursor
// Rationale: cross-round deltas show ~11us per dispatch boundary; this
// removes 4 of them and overlaps hist/fill latency with streaming work.
// ---------------------------------------------------------------------------
__global__ __launch_bounds__(256) void mid_coop(
    const float* __restrict__ Wself, const float* __restrict__ Wfwd,
    const float* __restrict__ rel, const float* __restrict__ Wr,
    const float* __restrict__ x, const int* __restrict__ ei,
    const int* __restrict__ etype, const float* __restrict__ ew,
    unsigned short* __restrict__ xb, unsigned short* __restrict__ Wb,
    float* __restrict__ rel_out, int* __restrict__ offs,
    int* __restrict__ bsum, uint2* __restrict__ meta,
    int nR, int nN, int nE) {
  namespace cg = cooperative_groups;
  cg::grid_group grid = cg::this_grid();
  const int t = threadIdx.x;
  const int G = (int)gridDim.x;
  const int NTH = G * 256;
  const int gt = (int)blockIdx.x * 256 + t;
  const int* dst = ei + nE;
  __shared__ int sd[256];
  __shared__ int carry;

  // ---- phase 0a: Wb swizzle (4096 units of 8 bf16) ----
  for (int u = gt; u < 2 * 8 * 4 * 64; u += NTH) {
    const int frag = u >> 6, lane = u & 63;
    const int mat = frag >> 5, ct = (frag >> 2) & 7, kt = frag & 3;
    const int q = lane >> 4, r = lane & 15;
    const float* W = mat ? Wfwd : Wself;
    const float* src = W + (ct * 16 + r) * D + kt * 32 + q * 8;
    unsigned short* dstp = Wb + frag * 512 + lane * 8;
    #pragma unroll
    for (int j = 0; j < 8; ++j) dstp[j] = f2bf(src[j]);
  }
  // ---- phase 0b: rel_out = rel @ Wr^T (scalar dots, L2-hot Wr) ----
  for (int o = gt; o < nR * D; o += NTH) {
    const int rr = o >> 7, c = o & 127;
    const float4* xr4 = (const float4*)(rel + rr * D);
    const float4* wr4 = (const float4*)(Wr + c * D);
    float ar = 0.f;
    #pragma unroll 8
    for (int k4 = 0; k4 < 32; ++k4) {
      const float4 xv = xr4[k4];
      const float4 wr = wr4[k4];
      ar += xv.x * wr.x + xv.y * wr.y + xv.z * wr.z + xv.w * wr.w;
    }
    rel_out[o] = ar;
  }
  // ---- phase 0c: zero offs ----
  for (int i = gt * 4; i < nN; i += NTH * 4) {
    if (i + 3 < nN) *(int4*)(offs + i) = make_int4(0, 0, 0, 0);
    else { for (int k = i; k < nN; ++k) offs[k] = 0; }
  }
  // ---- phase 0d: xb = bf16(x) ----
  {
    const int n8 = (nN * D) >> 3;            // D=128 -> exact
    for (int i8 = gt; i8 < n8; i8 += NTH) {
      const int i = i8 * 8;
      const float4 u0 = *(const float4*)(x + i);
      const float4 u1 = *(const float4*)(x + i + 4);
      const unsigned p0 = (unsigned)f2bf(u0.x) | ((unsigned)f2bf(u0.y) << 16);
      const unsigned p1 = (unsigned)f2bf(u0.z) | ((unsigned)f2bf(u0.w) << 16);
      const unsigned p2 = (unsigned)f2bf(u1.x) | ((unsigned)f2bf(u1.y) << 16);
      const unsigned p3 = (unsigned)f2bf(u1.z) | ((unsigned)f2bf(u1.w) << 16);
      *(int4*)(xb + i) = make_int4((int)p0, (int)p1, (int)p2, (int)p3);
    }
  }
  grid.sync();

  // ---- phase 1: histogram ----
  for (int e = gt; e < nE; e += NTH) atomicAdd(&offs[dst[e]], 1);
  grid.sync();

  // ---- phase 2a: chunk sums (256-elem chunks) ----
  const int nCh = (nN + 255) >> 8;
  for (int c = blockIdx.x; c < nCh; c += G) {
    const int i = c * 256 + t;
    sd[t] = (i < nN) ? offs[i] : 0;
    __syncthreads();
    for (int s = 128; s > 0; s >>= 1) {
      if (t < s) sd[t] += sd[t + s];
      __syncthreads();
    }
    if (t == 0) bsum[c] = sd[0];
    __syncthreads();
  }
  grid.sync();

  // ---- phase 2b: exclusive scan of bsum (block 0, serial tiles w/ carry) --
  if (blockIdx.x == 0) {
    if (t == 0) carry = 0;
    __syncthreads();
    for (int base = 0; base < nCh; base += 256) {
      const int i = base + t;
      const int v = (i < nCh) ? bsum[i] : 0;
      sd[t] = v;
      __syncthreads();
      for (int off = 1; off < 256; off <<= 1) {
        const int add = (t >= off) ? sd[t - off] : 0;
        __syncthreads();
        sd[t] += add;
        __syncthreads();
      }
      if (i < nCh) bsum[i] = sd[t] - v + carry;   // exclusive + carry
      __syncthreads();
      if (t == 0) carry += sd[255];
      __syncthreads();
    }
  }
  grid.sync();

  // ---- phase 2c: in-chunk exclusive scan + bsum offset ----
  for (int c = blockIdx.x; c < nCh; c += G) {
    const int i = c * 256 + t;
    const int v = (i < nN) ? offs[i] : 0;
    sd[t] = v;
    __syncthreads();
    for (int off = 1; off < 256; off <<= 1) {
      const int add = (t >= off) ? sd[t - off] : 0;
      __syncthreads();
      sd[t] += add;
      __syncthreads();
    }
    if (i < nN) offs[i] = sd[t] - v + bsum[c];
    __syncthreads();
  }
  grid.sync();

  // ---- phase 3: fill packed meta; offs -> bucket ends ----
  for (int e = gt; e < nE; e += NTH) {
    const int p = atomicAdd(&offs[dst[e]], 1);
    meta[p] = make_uint2((unsigned)ei[e] | ((unsigned)etype[e] << 20),
                         __float_as_uint(ew[e]));
  }
}

// ---------------------------------------------------------------------------
// Fallback (non-coop) pipeline kernels — identical to R5
// ---------------------------------------------------------------------------
__global__ __launch_bounds__(256) void prep_kernel(
    const float* __restrict__ Wself, const float* __restrict__ Wfwd,
    const float* __restrict__ rel, const float* __restrict__ Wr,
    const float* __restrict__ x, unsigned short* __restrict__ xb,
    unsigned short* __restrict__ Wb, float* __restrict__ rel_out,
    int* __restrict__ offs, int nR, int nN, int relBlocks, int zeroBlocks,
    int xbElems) {
  const int tid = threadIdx.x;
  const int bid = (int)blockIdx.x;
  if (bid < 16) {
    const int g = bid * 256 + tid;     // 0..4095
    const int frag = g >> 6, lane = g & 63;
    const int mat = frag >> 5, ct = (frag >> 2) & 7, kt = frag & 3;
    const int q = lane >> 4, r = lane & 15;
    const float* W = mat ? Wfwd : Wself;
    const float* src = W + (ct * 16 + r) * D + kt * 32 + q * 8;
    unsigned short* dstp = Wb + frag * 512 + lane * 8;
    #pragma unroll
    for (int j = 0; j < 8; ++j) dstp[j] = f2bf(src[j]);
  } else if (bid < 16 + relBlocks) {
    __shared__ float row[2][D];
    const int half = tid >> 7;
    const int c = tid & 127;
    const int rr = (bid - 16) * 2 + half;
    const int r2 = (rr < nR) ? rr : nR - 1;
    row[half][c] = rel[r2 * D + c];
    __syncthreads();
    const float4* xr4 = (const float4*)row[half];
    const float4* Wr4 = (const float4*)(Wr + c * D);
    float ar = 0.f;
    #pragma unroll 8
    for (int k4 = 0; k4 < 32; ++k4) {
      const float4 xv = xr4[k4];
      const float4 wr = Wr4[k4];
      ar += xv.x * wr.x + xv.y * wr.y + xv.z * wr.z + xv.w * wr.w;
    }
    if (rr < nR) rel_out[rr * D + c] = ar;
  } else if (bid < 16 + relBlocks + zeroBlocks) {
    const int i = (bid - 16 - relBlocks) * 256 + tid;
    const int e0 = i * 4;
    if (e0 < nN) {
      if (e0 + 3 < nN) ((int4*)offs)[i] = make_int4(0, 0, 0, 0);
      else { for (int k = e0; k < nN; ++k) offs[k] = 0; }
    }
  } else {
    const int i = ((bid - 16 - relBlocks - zeroBlocks) * 256 + tid) * 8;
    if (i + 7 < xbElems) {
      const float4 u0 = *(const float4*)(x + i);
      const float4 u1 = *(const float4*)(x + i + 4);
      const unsigned p0 = (unsigned)f2bf(u0.x) | ((unsigned)f2bf(u0.y) << 16);
      const unsigned p1 = (unsigned)f2bf(u0.z) | ((unsigned)f2bf(u0.w) << 16);
      const unsigned p2 = (unsigned)f2bf(u1.x) | ((unsigned)f2bf(u1.y) << 16);
      const unsigned p3 = (unsigned)f2bf(u1.z) | ((unsigned)f2bf(u1.w) << 16);
      *(int4*)(xb + i) = make_int4((int)p0, (int)p1, (int)p2, (int)p3);
    } else {
      for (int k = i; k < xbElems; ++k) xb[k] = f2bf(x[k]);
    }
  }
}

__global__ __launch_bounds__(256) void hist_kernel(
    const int* __restrict__ dst, int* __restrict__ offs, int nE) {
  const int i0 = ((int)blockIdx.x * 256 + (int)threadIdx.x) * 4;
  if (i0 + 3 < nE) {
    const int4 d4 = *(const int4*)(dst + i0);
    atomicAdd(&offs[d4.x], 1); atomicAdd(&offs[d4.y], 1);
    atomicAdd(&offs[d4.z], 1); atomicAdd(&offs[d4.w], 1);
  } else {
    for (int e = i0; e < nE && e < i0 + 4; ++e) atomicAdd(&offs[dst[e]], 1);
  }
}

__global__ __launch_bounds__(SCAN_B) void scan_pass1(
    const int* __restrict__ deg, int* __restrict__ bsum, int n) {
  __shared__ int sd[SCAN_B];
  const int i = blockIdx.x * SCAN_B + threadIdx.x;
  sd[threadIdx.x] = (i < n) ? deg[i] : 0;
  __syncthreads();
  for (int s = SCAN_B / 2; s > 0; s >>= 1) {
    if (threadIdx.x < s) sd[threadIdx.x] += sd[threadIdx.x + s];
    __syncthreads();
  }
  if (threadIdx.x == 0) bsum[blockIdx.x] = sd[0];
}

__global__ __launch_bounds__(SCAN_B) void scan_pass3(
    int* __restrict__ deg_offs, const int* __restrict__ bsum, int n) {
  __shared__ int sd[SCAN_B];
  __shared__ int boffs;
  const int t = threadIdx.x;
  int partial = 0;
  for (int j = t; j < (int)blockIdx.x; j += SCAN_B) partial += bsum[j];
  sd[t] = partial;
  __syncthreads();
  for (int s = SCAN_B / 2; s > 0; s >>= 1) {
    if (t < s) sd[t] += sd[t + s];
    __syncthreads();
  }
  if (t == 0) boffs = sd[0];
  __syncthreads();
  const int i = blockIdx.x * SCAN_B + t;
  const int v = (i < n) ? deg_offs[i] : 0;
  sd[t] = v;
  __syncthreads();
  for (int off = 1; off < SCAN_B; off <<= 1) {
    const int add = (t >= off) ? sd[t - off] : 0;
    __syncthreads();
    sd[t] += add;
    __syncthreads();
  }
  if (i < n) deg_offs[i] = sd[t] - v + boffs;
}

__global__ void fill_kernel(const int* __restrict__ src, const int* __restrict__ dstv,
                            const int* __restrict__ et, const float* __restrict__ ew,
                            int* __restrict__ cursor, uint2* __restrict__ meta, int nE) {
  const int e = blockIdx.x * blockDim.x + threadIdx.x;
  if (e < nE) {
    const int p = atomicAdd(&cursor[dstv[e]], 1);
    meta[p] = make_uint2((unsigned)src[e] | ((unsigned)et[e] << 20),
                         __float_as_uint(ew[e]));
  }
}

// ---------------------------------------------------------------------------
// fused_ag v5: aggregate-then-project, h in LDS only.
//  Agg: 32 lanes/node, group owns node, straight-line QUAD-processed inner
//  loop (4 edges in flight = depth-4 MLP; v4 depth-2 at VGPR 32 left huge
//  register headroom). (256,8): 8 blocks/CU (17.4KB LDS).
//  GEMM: 4 waves = (row-half, col-half); acc = x@Ws + hi@Wf + lo@Wf.
// ---------------------------------------------------------------------------
__global__ __launch_bounds__(256, 8) void fused_ag(
    const unsigned short* __restrict__ xb, const float4* __restrict__ rel4,
    const uint2* __restrict__ meta, const int* __restrict__ offs,
    const unsigned short* __restrict__ Wb, const float* __restrict__ bias,
    float* __restrict__ out,
    int nN, int useGlobalH, const float* __restrict__ hg) {
  __shared__ float hsm[NT][HPAD];
  __shared__ int bndv[NT + 1];
  const int tid = threadIdx.x;
  const int g0 = blockIdx.x * NT;
  const uint2* xb2 = (const uint2*)xb;

  if (!useGlobalH) {
    if (tid <= NT) {
      int v;
      if (tid == 0) v = (g0 == 0) ? 0 : offs[g0 - 1];
      else { int idx = g0 + tid - 1; if (idx > nN - 1) idx = nN - 1; v = offs[idx]; }
      bndv[tid] = v;
    }
    __syncthreads();

    const int g = tid >> 5;          // group 0..7
    const int l32 = tid & 31;
    #pragma unroll
    for (int r = 0; r < NT / 8; ++r) {
      const int nl = r * 8 + g;
      const int n = g0 + nl;
      if (n < nN) {
        float a0 = 0.f, a1 = 0.f, a2 = 0.f, a3 = 0.f;
        const int start = bndv[nl], end = bndv[nl + 1];
        for (int base = start; base < end; base += 32) {
          const int m = (end - base < 32) ? (end - base) : 32;
          uint2 mv = make_uint2(0u, 0u);
          if (l32 < m) mv = meta[base + l32];
          int jb = 0;
          for (; jb + 4 <= m; jb += 4) {
            const unsigned pk0 = (unsigned)__shfl((int)mv.x, jb, 32);
            const unsigned pk1 = (unsigned)__shfl((int)mv.x, jb + 1, 32);
            const unsigned pk2 = (unsigned)__shfl((int)mv.x, jb + 2, 32);
            const unsigned pk3 = (unsigned)__shfl((int)mv.x, jb + 3, 32);
            const float w0 = __uint_as_float(__shfl((int)mv.y, jb, 32));
            const float w1 = __uint_as_float(__shfl((int)mv.y, jb + 1, 32));
            const float w2 = __uint_as_float(__shfl((int)mv.y, jb + 2, 32));
            const float w3 = __uint_as_float(__shfl((int)mv.y, jb + 3, 32));
            const uint2 av0 = xb2[(size_t)(pk0 & 0xFFFFFu) * 32 + l32];
            const float4 rv0 = rel4[(size_t)(pk0 >> 20) * 32 + l32];
            const uint2 av1 = xb2[(size_t)(pk1 & 0xFFFFFu) * 32 + l32];
            const float4 rv1 = rel4[(size_t)(pk1 >> 20) * 32 + l32];
            const uint2 av2 = xb2[(size_t)(pk2 & 0xFFFFFu) * 32 + l32];
            const float4 rv2 = rel4[(size_t)(pk2 >> 20) * 32 + l32];
            const uint2 av3 = xb2[(size_t)(pk3 & 0xFFFFFu) * 32 + l32];
            const float4 rv3 = rel4[(size_t)(pk3 >> 20) * 32 + l32];
            a0 += w0 * (bflo(av0.x) - rv0.x);
            a1 += w0 * (bfhi(av0.x) - rv0.y);
            a2 += w0 * (bflo(av0.y) - rv0.z);
            a3 += w0 * (bfhi(av0.y) - rv0.w);
            a0 += w1 * (bflo(av1.x) - rv1.x);
            a1 += w1 * (bfhi(av1.x) - rv1.y);
            a2 += w1 * (bflo(av1.y) - rv1.z);
            a3 += w1 * (bfhi(av1.y) - rv1.w);
            a0 += w2 * (bflo(av2.x) - rv2.x);
            a1 += w2 * (bfhi(av2.x) - rv2.y);
            a2 += w2 * (bflo(av2.y) - rv2.z);
            a3 += w2 * (bfhi(av2.y) - rv2.w);
            a0 += w3 * (bflo(av3.x) - rv3.x);
            a1 += w3 * (bfhi(av3.x) - rv3.y);
            a2 += w3 * (bflo(av3.y) - rv3.z);
            a3 += w3 * (bfhi(av3.y) - rv3.w);
          }
          for (; jb < m; ++jb) {
            const unsigned pk = (unsigned)__shfl((int)mv.x, jb, 32);
            const float wv = __uint_as_float(__shfl((int)mv.y, jb, 32));
            const uint2 av = xb2[(size_t)(pk & 0xFFFFFu) * 32 + l32];
            const float4 rv = rel4[(size_t)(pk >> 20) * 32 + l32];
            a0 += wv * (bflo(av.x) - rv.x);
            a1 += wv * (bfhi(av.x) - rv.y);
            a2 += wv * (bflo(av.y) - rv.z);
            a3 += wv * (bfhi(av.y) - rv.w);
          }
        }
        *(float4*)&hsm[nl][l32 * 4] = make_float4(a0, a1, a2, a3);
      }
    }
  } else {
    for (int idx = tid; idx < NT * 32; idx += 256) {
      const int rr = idx >> 5, cc = (idx & 31) * 4;
      const int n = g0 + rr;
      float4 v = make_float4(0.f, 0.f, 0.f, 0.f);
      if (n < nN && hg) v = *(const float4*)(hg + (size_t)n * D + cc);
      *(float4*)&hsm[rr][cc] = v;
    }
  }
  __syncthreads();

  // ---- GEMM phase: wave w = (row-half w>>1, col-half w&1) -------------
  const int w = tid >> 6, lane = tid & 63;
  const int q = lane >> 4, r = lane & 15;
  const int rowbase = (w >> 1) * 16;
  const int ch = w & 1;
  const int lr = rowbase + r;
  int grow = g0 + lr; if (grow >= nN) grow = nN - 1;

  f32x4 acc[4];
  #pragma unroll
  for (int c2 = 0; c2 < 4; ++c2) acc[c2] = (f32x4)0.f;

  #pragma unroll
  for (int kt = 0; kt < 4; ++kt) {
    const bf16x8 xa = *(const bf16x8*)(xb + (size_t)grow * D + kt * 32 + q * 8);
    const float* hp = &hsm[lr][kt * 32 + q * 8];
    const float4 h0 = *(const float4*)hp;
    const float4 h1 = *(const float4*)(hp + 4);
    const float hv[8] = {h0.x, h0.y, h0.z, h0.w, h1.x, h1.y, h1.z, h1.w};
    bf16x8 hi, lo;
    #pragma unroll
    for (int j = 0; j < 8; ++j) {
      const unsigned short hb = f2bf(hv[j]);
      hi[j] = (short)hb;
      lo[j] = (short)f2bf(hv[j] - bf2f(hb));
    }
    #pragma unroll
    for (int c2 = 0; c2 < 4; ++c2) {
      const int ct = ch * 4 + c2;
      const bf16x8 bS = *(const bf16x8*)(Wb + ((0 * 8 + ct) * 4 + kt) * 512 + lane * 8);
      const bf16x8 bF = *(const bf16x8*)(Wb + ((1 * 8 + ct) * 4 + kt) * 512 + lane * 8);
      acc[c2] = __builtin_amdgcn_mfma_f32_16x16x32_bf16(xa, bS, acc[c2], 0, 0, 0);
      acc[c2] = __builtin_amdgcn_mfma_f32_16x16x32_bf16(hi, bF, acc[c2], 0, 0, 0);
      acc[c2] = __builtin_amdgcn_mfma_f32_16x16x32_bf16(lo, bF, acc[c2], 0, 0, 0);
    }
  }

  #pragma unroll
  for (int c2 = 0; c2 < 4; ++c2) {
    const int col = ch * 64 + c2 * 16 + r;
    const float bv = bias[col];
    #pragma unroll
    for (int reg = 0; reg < 4; ++reg) {
      const int row = g0 + rowbase + q * 4 + reg;
      if (row < nN) out[(size_t)row * D + col] = acc[c2][reg] + bv;
    }
  }
}

// ---------------------------------------------------------------------------
// Fallbacks (never taken at harness sizes)
// ---------------------------------------------------------------------------
__global__ __launch_bounds__(256) void hzero(float* __restrict__ h, int n4) {
  const int i = blockIdx.x * 256 + threadIdx.x;
  if (i < n4) ((int4*)h)[i] = make_int4(0, 0, 0, 0);
}

__global__ __launch_bounds__(256) void hscatter(
    const uint4* __restrict__ xb4, const float* __restrict__ rel,
    const int* __restrict__ ei, const int* __restrict__ etype,
    const float* __restrict__ ew, float* __restrict__ h, int nE) {
  const int e = blockIdx.x * 16 + ((int)threadIdx.x >> 4);
  if (e >= nE) return;
  const int l = threadIdx.x & 15;
  const int s = ei[e], d = ei[nE + e], t = etype[e];
  const float wv = ew[e];
  const uint4 a = xb4[(size_t)s * 16 + l];
  const float4 r0 = ((const float4*)(rel + (size_t)t * D))[l * 2];
  const float4 r1 = ((const float4*)(rel + (size_t)t * D))[l * 2 + 1];
  float* o = h + (size_t)d * D + l * 8;
  atomicAdd(o + 0, wv * (bflo(a.x) - r0.x));
  atomicAdd(o + 1, wv * (bfhi(a.x) - r0.y));
  atomicAdd(o + 2, wv * (bflo(a.y) - r0.z));
  atomicAdd(o + 3, wv * (bfhi(a.y) - r0.w));
  atomicAdd(o + 4, wv * (bflo(a.z) - r1.x));
  atomicAdd(o + 5, wv * (bfhi(a.z) - r1.y));
  atomicAdd(o + 6, wv * (bflo(a.w) - r1.z));
  atomicAdd(o + 7, wv * (bfhi(a.w) - r1.w));
}

__global__ __launch_bounds__(256) void edge_scatter_f32(
    const float* __restrict__ x, const float* __restrict__ rel,
    const float* __restrict__ Wfwd,
    const int* __restrict__ ei, const int* __restrict__ etype,
    const float* __restrict__ ew, float* __restrict__ out, int nE) {
  __shared__ float msg[2][D];
  const int half = (int)threadIdx.x >> 7;
  const int c = threadIdx.x & 127;
  const int e = blockIdx.x * 2 + half;
  if (e >= nE) return;
  const int s = ei[e], d = ei[nE + e], t = etype[e];
  msg[half][c] = x[(size_t)s * D + c] - rel[(size_t)t * D + c];
  __syncthreads();
  float a = 0.f;
  #pragma unroll 8
  for (int k = 0; k < D; ++k) a += msg[half][k] * Wfwd[c * D + k];
  atomicAdd(&out[(size_t)d * D + c], ew[e] * a);
}

// ---------------------------------------------------------------------------
extern "C" void kernel_launch(void* const* d_in, const int* in_sizes, int n_in,
                              void* d_out, int out_size, void* d_ws, size_t ws_size,
                              hipStream_t stream) {
  const float* x      = (const float*)d_in[0];
  const int*   ei     = (const int*)d_in[1];
  const int*   etype  = (const int*)d_in[2];
  const float* rel    = (const float*)d_in[3];
  const float* ew     = (const float*)d_in[4];
  const float* Wself  = (const float*)d_in[5];
  const float* Wfwd   = (const float*)d_in[6];
  const float* Wrel   = (const float*)d_in[7];
  const float* bias   = (const float*)d_in[8];

  const int nN = in_sizes[0] / D;       // 100000
  const int nE = in_sizes[2];           // 625000
  const int nR = in_sizes[3] / D;       // 200

  float* out     = (float*)d_out;
  float* rel_out = (float*)d_out + (size_t)nN * D;

  // workspace carve-up (256B-aligned)
  char* w = (char*)d_ws;
  size_t off = 0;
  auto carve = [&](size_t bytes) {
    char* p = w + off;
    off = (off + bytes + 255) & ~(size_t)255;
    return p;
  };
  unsigned short* xb  = (unsigned short*)carve((size_t)nN * D * sizeof(unsigned short));
  unsigned short* Wb  = (unsigned short*)carve(2 * 8 * 4 * 512 * sizeof(unsigned short));
  int*   offs = (int*)carve((size_t)nN * sizeof(int));
  uint2* meta = (uint2*)carve((size_t)nE * sizeof(uint2));
  int*   bsum = (int*)carve(4096 * sizeof(int));
  const size_t need = off;

  const int* dst = ei + nE;
  const int nb = (nN + SCAN_B - 1) / SCAN_B;
  const int relBlocks  = (nR + 1) / 2;
  const int zeroBlocks = (nN + 1023) / 1024;
  const int xbBlocks   = (int)(((size_t)nN * D + 2047) / 2048);
  const int histBlocks = (nE + 1023) / 1024;
  const int aggBlocks  = (nN + NT - 1) / NT;

  const bool csr_ok = (need <= ws_size) && (nb <= 4096) &&
                      (nN < (1 << 20)) && (nR <= 4096);
  const size_t hBytes = (size_t)nN * D * sizeof(float);
  const bool h_ok = ((size_t)nN * D * sizeof(unsigned short) + 256 + hBytes) <= ws_size;

  // one-time host-side cooperative-launch capability check (pure queries,
  // graph-capture safe; cached across calls)
  static int g_coop = -1;
  static int g_blocks = 0;
  if (g_coop < 0) {
    int dev = 0;
    (void)hipGetDevice(&dev);
    int can = 0;
    (void)hipDeviceGetAttribute(&can, hipDeviceAttributeCooperativeLaunch, dev);
    int numCU = 0;
    (void)hipDeviceGetAttribute(&numCU, hipDeviceAttributeMultiprocessorCount, dev);
    int maxB = 0;
    (void)hipOccupancyMaxActiveBlocksPerMultiprocessor(&maxB, mid_coop, 256, 0);
    int cap = maxB * numCU;
    g_blocks = cap < 2048 ? cap : 2048;
    g_coop = (can && g_blocks >= 64) ? 1 : 0;
  }

  if (csr_ok && g_coop) {
    // 2 dispatches total: coop {prep+hist+scan+fill}, then fused agg+GEMM
    void* args[] = {(void*)&Wself, (void*)&Wfwd, (void*)&rel, (void*)&Wrel,
                    (void*)&x, (void*)&ei, (void*)&etype, (void*)&ew,
                    (void*)&xb, (void*)&Wb, (void*)&rel_out, (void*)&offs,
                    (void*)&bsum, (void*)&meta,
                    (void*)&nR, (void*)&nN, (void*)&nE};
    (void)hipLaunchCooperativeKernel(mid_coop, dim3(g_blocks), dim3(256),
                                     args, 0, stream);
    fused_ag<<<aggBlocks, 256, 0, stream>>>(
        xb, (const float4*)rel, meta, offs, Wb, bias, out,
        nN, 0, (const float*)0);
  } else {
    prep_kernel<<<16 + relBlocks + zeroBlocks + xbBlocks, 256, 0, stream>>>(
        Wself, Wfwd, rel, Wrel, x, xb, Wb, rel_out, offs, nR, nN,
        relBlocks, zeroBlocks, nN * D);
    if (csr_ok) {
      hist_kernel<<<histBlocks, 256, 0, stream>>>(dst, offs, nE);
      scan_pass1<<<nb, SCAN_B, 0, stream>>>(offs, bsum, nN);
      scan_pass3<<<nb, SCAN_B, 0, stream>>>(offs, bsum, nN);
      fill_kernel<<<(nE + 255) / 256, 256, 0, stream>>>(ei, dst, etype, ew, offs, meta, nE);
      fused_ag<<<aggBlocks, 256, 0, stream>>>(
          xb, (const float4*)rel, meta, offs, Wb, bias, out,
          nN, 0, (const float*)0);
    } else if (h_ok) {
      float* h = (float*)(w + (((size_t)nN * D * sizeof(unsigned short) + 255) & ~(size_t)255));
      const int n4 = (nN * D) / 4;
      hzero<<<(n4 + 255) / 256, 256, 0, stream>>>(h, n4);
      hscatter<<<(nE + 15) / 16, 256, 0, stream>>>(
          (const uint4*)xb, rel, ei, etype, ew, h, nE);
      fused_ag<<<aggBlocks, 256, 0, stream>>>(
          xb, (const float4*)rel, (const uint2*)0, (const int*)0,
          Wb, bias, out, nN, 1, h);
    } else {
      fused_ag<<<aggBlocks, 256, 0, stream>>>(
          xb, (const float4*)rel, (const uint2*)0, (const int*)0,
          Wb, bias, out, nN, 1, (const float*)0);
      edge_scatter_f32<<<(nE + 1) / 2, 256, 0, stream>>>(
          x, rel, Wfwd, ei, etype, ew, out, nE);
    }
  }
}

// Round 7
// 250.722 us; speedup vs baseline: 2.6415x; 2.6415x over previous
//
#include <hip/hip_runtime.h>

#define D 128
#define SCAN_B 256
#define NT 32            // nodes per fused_ag block
#define HPAD 132         // padded LDS row (floats) — breaks stride-128 bank alias

typedef short bf16x8 __attribute__((ext_vector_type(8)));
typedef float f32x4 __attribute__((ext_vector_type(4)));

static __device__ __forceinline__ unsigned short f2bf(float f) {
  union { float f; unsigned u; } v; v.f = f;
  return (unsigned short)((v.u + 0x7FFF + ((v.u >> 16) & 1)) >> 16);   // RNE
}
static __device__ __forceinline__ float bf2f(unsigned short h) {
  union { unsigned u; float f; } v; v.u = ((unsigned)h) << 16;
  return v.f;
}
static __device__ __forceinline__ float bflo(unsigned u) {
  union { unsigned u; float f; } v; v.u = u << 16; return v.f;
}
static __device__ __forceinline__ float bfhi(unsigned u) {
  union { unsigned u; float f; } v; v.u = u & 0xFFFF0000u; return v.f;
}

// ---------------------------------------------------------------------------
// prep_kernel (small): blocks [0,16)     : Wself/Wfwd -> bf16 swizzled Wb
//                      [16,+relBlocks)   : rel_out = rel @ Wr^T
//                      [..,+zeroBlocks)  : zero offs (+ first block zeros bsum)
// xb conversion moved OUT (co-scheduled with histogram in xb_hist).
// ---------------------------------------------------------------------------
__global__ __launch_bounds__(256) void prep_kernel(
    const float* __restrict__ Wself, const float* __restrict__ Wfwd,
    const float* __restrict__ rel, const float* __restrict__ Wr,
    unsigned short* __restrict__ Wb, float* __restrict__ rel_out,
    int* __restrict__ offs, int* __restrict__ bsum,
    int nR, int nN, int relBlocks, int nb) {
  const int tid = threadIdx.x;
  const int bid = (int)blockIdx.x;
  if (bid < 16) {
    // Wb[frag*512 + lane*8 + j]: frag=((mat*8+ct)*4+kt); lane(q=lane>>4,r=lane&15)
    // holds W[ct*16+r][kt*32+q*8+j].  mat0=Wself, mat1=Wfwd.
    const int g = bid * 256 + tid;     // 0..4095
    const int frag = g >> 6, lane = g & 63;
    const int mat = frag >> 5, ct = (frag >> 2) & 7, kt = frag & 3;
    const int q = lane >> 4, r = lane & 15;
    const float* W = mat ? Wfwd : Wself;
    const float* src = W + (ct * 16 + r) * D + kt * 32 + q * 8;
    unsigned short* dstp = Wb + frag * 512 + lane * 8;
    #pragma unroll
    for (int j = 0; j < 8; ++j) dstp[j] = f2bf(src[j]);
  } else if (bid < 16 + relBlocks) {
    __shared__ float row[2][D];
    const int half = tid >> 7;                 // 0/1: which rel row
    const int c = tid & 127;
    const int rr = (bid - 16) * 2 + half;
    const int r2 = (rr < nR) ? rr : nR - 1;
    row[half][c] = rel[r2 * D + c];
    __syncthreads();
    const float4* xr4 = (const float4*)row[half];
    const float4* Wr4 = (const float4*)(Wr + c * D);
    float ar = 0.f;
    #pragma unroll 8
    for (int k4 = 0; k4 < 32; ++k4) {
      const float4 xv = xr4[k4];
      const float4 wr = Wr4[k4];
      ar += xv.x * wr.x + xv.y * wr.y + xv.z * wr.z + xv.w * wr.w;
    }
    if (rr < nR) rel_out[rr * D + c] = ar;
  } else {
    const int zb = bid - 16 - relBlocks;
    if (zb == 0) {                      // also zero scan-aggregate buffer
      for (int j = tid; j < nb; j += 256) bsum[j] = 0;
    }
    const int i = zb * 256 + tid;       // int4 index
    const int e0 = i * 4;
    if (e0 < nN) {
      if (e0 + 3 < nN) ((int4*)offs)[i] = make_int4(0, 0, 0, 0);
      else { for (int k = e0; k < nN; ++k) offs[k] = 0; }
    }
  }
}

// ---------------------------------------------------------------------------
// xb_hist: blocks [0,xbBlocks): xb = bf16(x) (streaming) — hides the
//          atomic-latency-bound histogram in blocks [xbBlocks, ...).
// ---------------------------------------------------------------------------
__global__ __launch_bounds__(256) void xb_hist(
    const float* __restrict__ x, unsigned short* __restrict__ xb,
    const int* __restrict__ dst, int* __restrict__ offs,
    int nElems, int nE, int xbBlocks) {
  if ((int)blockIdx.x < xbBlocks) {
    const int i = ((int)blockIdx.x * 256 + (int)threadIdx.x) * 8;
    if (i + 7 < nElems) {
      const float4 u0 = *(const float4*)(x + i);
      const float4 u1 = *(const float4*)(x + i + 4);
      const unsigned p0 = (unsigned)f2bf(u0.x) | ((unsigned)f2bf(u0.y) << 16);
      const unsigned p1 = (unsigned)f2bf(u0.z) | ((unsigned)f2bf(u0.w) << 16);
      const unsigned p2 = (unsigned)f2bf(u1.x) | ((unsigned)f2bf(u1.y) << 16);
      const unsigned p3 = (unsigned)f2bf(u1.z) | ((unsigned)f2bf(u1.w) << 16);
      *(int4*)(xb + i) = make_int4((int)p0, (int)p1, (int)p2, (int)p3);
    } else {
      for (int k = i; k < nElems; ++k) xb[k] = f2bf(x[k]);
    }
  } else {
    const int i0 = (((int)blockIdx.x - xbBlocks) * 256 + (int)threadIdx.x) * 4;
    if (i0 + 3 < nE) {
      const int4 d4 = *(const int4*)(dst + i0);
      atomicAdd(&offs[d4.x], 1); atomicAdd(&offs[d4.y], 1);
      atomicAdd(&offs[d4.z], 1); atomicAdd(&offs[d4.w], 1);
    } else {
      for (int e = i0; e < nE && e < i0 + 4; ++e) atomicAdd(&offs[dst[e]], 1);
    }
  }
}

// ---------------------------------------------------------------------------
// scan_single: ONE-dispatch exclusive scan via decoupled-lookback AGGREGATES.
//  Each block: local inclusive scan -> publish (total<<1)|1 into agg[b]
//  (data+ready packed in one word: no fence needed) -> sum all predecessors'
//  published aggregates (parallel spins, no serial chain) -> write exclusive.
//  SAFETY: grid must be fully co-resident: host only uses this when
//  nb <= 512 (>=2 blocks/CU guaranteed by __launch_bounds__(256,2) x 256 CU).
//  Publish happens BEFORE any spin, so residency => progress.
//  Totals must fit 31 bits (nE < 2^30) — guaranteed by host guard.
// ---------------------------------------------------------------------------
__global__ __launch_bounds__(256, 2) void scan_single(
    int* __restrict__ deg_offs, int* __restrict__ agg, int n) {
  __shared__ int sd[256];
  __shared__ int sp[256];
  __shared__ int boffs;
  const int t = threadIdx.x;
  const int b = (int)blockIdx.x;
  const int i = b * 256 + t;
  const int v = (i < n) ? deg_offs[i] : 0;
  sd[t] = v;
  __syncthreads();
  for (int off = 1; off < 256; off <<= 1) {
    const int add = (t >= off) ? sd[t - off] : 0;
    __syncthreads();
    sd[t] += add;
    __syncthreads();
  }
  if (t == 0) atomicExch(&agg[b], (sd[255] << 1) | 1);   // publish FIRST
  int partial = 0;
  for (int j = t; j < b; j += 256) {
    int a;
    while (((a = atomicOr(&agg[j], 0)) & 1) == 0) __builtin_amdgcn_s_sleep(4);
    partial += (a >> 1);
  }
  sp[t] = partial;
  __syncthreads();
  for (int s = 128; s > 0; s >>= 1) {
    if (t < s) sp[t] += sp[t + s];
    __syncthreads();
  }
  if (t == 0) boffs = sp[0];
  __syncthreads();
  if (i < n) deg_offs[i] = sd[t] - v + boffs;   // exclusive global
}

// ---------------------------------------------------------------------------
// Fallback two-kernel scan (nb > 512)
// ---------------------------------------------------------------------------
__global__ __launch_bounds__(SCAN_B) void scan_pass1(
    const int* __restrict__ deg, int* __restrict__ bsum, int n) {
  __shared__ int sd[SCAN_B];
  const int i = blockIdx.x * SCAN_B + threadIdx.x;
  sd[threadIdx.x] = (i < n) ? deg[i] : 0;
  __syncthreads();
  for (int s = SCAN_B / 2; s > 0; s >>= 1) {
    if (threadIdx.x < s) sd[threadIdx.x] += sd[threadIdx.x + s];
    __syncthreads();
  }
  if (threadIdx.x == 0) bsum[blockIdx.x] = sd[0];
}

__global__ __launch_bounds__(SCAN_B) void scan_pass3(
    int* __restrict__ deg_offs, const int* __restrict__ bsum, int n) {
  __shared__ int sd[SCAN_B];
  __shared__ int boffs;
  const int t = threadIdx.x;
  int partial = 0;
  for (int j = t; j < (int)blockIdx.x; j += SCAN_B) partial += bsum[j];
  sd[t] = partial;
  __syncthreads();
  for (int s = SCAN_B / 2; s > 0; s >>= 1) {
    if (t < s) sd[t] += sd[t + s];
    __syncthreads();
  }
  if (t == 0) boffs = sd[0];
  __syncthreads();
  const int i = blockIdx.x * SCAN_B + t;
  const int v = (i < n) ? deg_offs[i] : 0;
  sd[t] = v;
  __syncthreads();
  for (int off = 1; off < SCAN_B; off <<= 1) {
    const int add = (t >= off) ? sd[t - off] : 0;
    __syncthreads();
    sd[t] += add;
    __syncthreads();
  }
  if (i < n) deg_offs[i] = sd[t] - v + boffs;
}

// ---------------------------------------------------------------------------
// fill: CSR-ordered PACKED metadata. meta[p] = {src | et<<20, bits(ew)}.
// After this, offs[n] == end of bucket n (cursor advanced to end).
// ---------------------------------------------------------------------------
__global__ void fill_kernel(const int* __restrict__ src, const int* __restrict__ dstv,
                            const int* __restrict__ et, const float* __restrict__ ew,
                            int* __restrict__ cursor, uint2* __restrict__ meta, int nE) {
  const int e = blockIdx.x * blockDim.x + threadIdx.x;
  if (e < nE) {
    const int p = atomicAdd(&cursor[dstv[e]], 1);
    meta[p] = make_uint2((unsigned)src[e] | ((unsigned)et[e] << 20),
                         __float_as_uint(ew[e]));
  }
}

// ---------------------------------------------------------------------------
// fused_ag: aggregate-then-project, h in LDS only.
//  Agg: 32 lanes/node, group owns node, straight-line QUAD-processed inner
//  loop (depth-4 MLP). (256,8): 8 blocks/CU (17.4KB LDS).
//  GEMM: 4 waves = (row-half, col-half); acc = x@Ws + hi@Wf + lo@Wf.
// ---------------------------------------------------------------------------
__global__ __launch_bounds__(256, 8) void fused_ag(
    const unsigned short* __restrict__ xb, const float4* __restrict__ rel4,
    const uint2* __restrict__ meta, const int* __restrict__ offs,
    const unsigned short* __restrict__ Wb, const float* __restrict__ bias,
    float* __restrict__ out,
    int nN, int useGlobalH, const float* __restrict__ hg) {
  __shared__ float hsm[NT][HPAD];
  __shared__ int bndv[NT + 1];
  const int tid = threadIdx.x;
  const int g0 = blockIdx.x * NT;
  const uint2* xb2 = (const uint2*)xb;

  if (!useGlobalH) {
    if (tid <= NT) {
      int v;
      if (tid == 0) v = (g0 == 0) ? 0 : offs[g0 - 1];
      else { int idx = g0 + tid - 1; if (idx > nN - 1) idx = nN - 1; v = offs[idx]; }
      bndv[tid] = v;
    }
    __syncthreads();

    const int g = tid >> 5;          // group 0..7
    const int l32 = tid & 31;
    #pragma unroll
    for (int r = 0; r < NT / 8; ++r) {
      const int nl = r * 8 + g;
      const int n = g0 + nl;
      if (n < nN) {
        float a0 = 0.f, a1 = 0.f, a2 = 0.f, a3 = 0.f;
        const int start = bndv[nl], end = bndv[nl + 1];
        for (int base = start; base < end; base += 32) {
          const int m = (end - base < 32) ? (end - base) : 32;
          uint2 mv = make_uint2(0u, 0u);
          if (l32 < m) mv = meta[base + l32];
          int jb = 0;
          for (; jb + 4 <= m; jb += 4) {
            const unsigned pk0 = (unsigned)__shfl((int)mv.x, jb, 32);
            const unsigned pk1 = (unsigned)__shfl((int)mv.x, jb + 1, 32);
            const unsigned pk2 = (unsigned)__shfl((int)mv.x, jb + 2, 32);
            const unsigned pk3 = (unsigned)__shfl((int)mv.x, jb + 3, 32);
            const float w0 = __uint_as_float(__shfl((int)mv.y, jb, 32));
            const float w1 = __uint_as_float(__shfl((int)mv.y, jb + 1, 32));
            const float w2 = __uint_as_float(__shfl((int)mv.y, jb + 2, 32));
            const float w3 = __uint_as_float(__shfl((int)mv.y, jb + 3, 32));
            const uint2 av0 = xb2[(size_t)(pk0 & 0xFFFFFu) * 32 + l32];
            const float4 rv0 = rel4[(size_t)(pk0 >> 20) * 32 + l32];
            const uint2 av1 = xb2[(size_t)(pk1 & 0xFFFFFu) * 32 + l32];
            const float4 rv1 = rel4[(size_t)(pk1 >> 20) * 32 + l32];
            const uint2 av2 = xb2[(size_t)(pk2 & 0xFFFFFu) * 32 + l32];
            const float4 rv2 = rel4[(size_t)(pk2 >> 20) * 32 + l32];
            const uint2 av3 = xb2[(size_t)(pk3 & 0xFFFFFu) * 32 + l32];
            const float4 rv3 = rel4[(size_t)(pk3 >> 20) * 32 + l32];
            a0 += w0 * (bflo(av0.x) - rv0.x);
            a1 += w0 * (bfhi(av0.x) - rv0.y);
            a2 += w0 * (bflo(av0.y) - rv0.z);
            a3 += w0 * (bfhi(av0.y) - rv0.w);
            a0 += w1 * (bflo(av1.x) - rv1.x);
            a1 += w1 * (bfhi(av1.x) - rv1.y);
            a2 += w1 * (bflo(av1.y) - rv1.z);
            a3 += w1 * (bfhi(av1.y) - rv1.w);
            a0 += w2 * (bflo(av2.x) - rv2.x);
            a1 += w2 * (bfhi(av2.x) - rv2.y);
            a2 += w2 * (bflo(av2.y) - rv2.z);
            a3 += w2 * (bfhi(av2.y) - rv2.w);
            a0 += w3 * (bflo(av3.x) - rv3.x);
            a1 += w3 * (bfhi(av3.x) - rv3.y);
            a2 += w3 * (bflo(av3.y) - rv3.z);
            a3 += w3 * (bfhi(av3.y) - rv3.w);
          }
          for (; jb < m; ++jb) {
            const unsigned pk = (unsigned)__shfl((int)mv.x, jb, 32);
            const float wv = __uint_as_float(__shfl((int)mv.y, jb, 32));
            const uint2 av = xb2[(size_t)(pk & 0xFFFFFu) * 32 + l32];
            const float4 rv = rel4[(size_t)(pk >> 20) * 32 + l32];
            a0 += wv * (bflo(av.x) - rv.x);
            a1 += wv * (bfhi(av.x) - rv.y);
            a2 += wv * (bflo(av.y) - rv.z);
            a3 += wv * (bfhi(av.y) - rv.w);
          }
        }
        *(float4*)&hsm[nl][l32 * 4] = make_float4(a0, a1, a2, a3);
      }
    }
  } else {
    for (int idx = tid; idx < NT * 32; idx += 256) {
      const int rr = idx >> 5, cc = (idx & 31) * 4;
      const int n = g0 + rr;
      float4 v = make_float4(0.f, 0.f, 0.f, 0.f);
      if (n < nN && hg) v = *(const float4*)(hg + (size_t)n * D + cc);
      *(float4*)&hsm[rr][cc] = v;
    }
  }
  __syncthreads();

  // ---- GEMM phase: wave w = (row-half w>>1, col-half w&1) -------------
  const int w = tid >> 6, lane = tid & 63;
  const int q = lane >> 4, r = lane & 15;
  const int rowbase = (w >> 1) * 16;
  const int ch = w & 1;
  const int lr = rowbase + r;
  int grow = g0 + lr; if (grow >= nN) grow = nN - 1;

  f32x4 acc[4];
  #pragma unroll
  for (int c2 = 0; c2 < 4; ++c2) acc[c2] = (f32x4)0.f;

  #pragma unroll
  for (int kt = 0; kt < 4; ++kt) {
    const bf16x8 xa = *(const bf16x8*)(xb + (size_t)grow * D + kt * 32 + q * 8);
    const float* hp = &hsm[lr][kt * 32 + q * 8];
    const float4 h0 = *(const float4*)hp;
    const float4 h1 = *(const float4*)(hp + 4);
    const float hv[8] = {h0.x, h0.y, h0.z, h0.w, h1.x, h1.y, h1.z, h1.w};
    bf16x8 hi, lo;
    #pragma unroll
    for (int j = 0; j < 8; ++j) {
      const unsigned short hb = f2bf(hv[j]);
      hi[j] = (short)hb;
      lo[j] = (short)f2bf(hv[j] - bf2f(hb));
    }
    #pragma unroll
    for (int c2 = 0; c2 < 4; ++c2) {
      const int ct = ch * 4 + c2;
      const bf16x8 bS = *(const bf16x8*)(Wb + ((0 * 8 + ct) * 4 + kt) * 512 + lane * 8);
      const bf16x8 bF = *(const bf16x8*)(Wb + ((1 * 8 + ct) * 4 + kt) * 512 + lane * 8);
      acc[c2] = __builtin_amdgcn_mfma_f32_16x16x32_bf16(xa, bS, acc[c2], 0, 0, 0);
      acc[c2] = __builtin_amdgcn_mfma_f32_16x16x32_bf16(hi, bF, acc[c2], 0, 0, 0);
      acc[c2] = __builtin_amdgcn_mfma_f32_16x16x32_bf16(lo, bF, acc[c2], 0, 0, 0);
    }
  }

  #pragma unroll
  for (int c2 = 0; c2 < 4; ++c2) {
    const int col = ch * 64 + c2 * 16 + r;
    const float bv = bias[col];
    #pragma unroll
    for (int reg = 0; reg < 4; ++reg) {
      const int row = g0 + rowbase + q * 4 + reg;
      if (row < nN) out[(size_t)row * D + col] = acc[c2][reg] + bv;
    }
  }
}

// ---------------------------------------------------------------------------
// Fallbacks (never taken at harness sizes)
// ---------------------------------------------------------------------------
__global__ __launch_bounds__(256) void hzero(float* __restrict__ h, int n4) {
  const int i = blockIdx.x * 256 + threadIdx.x;
  if (i < n4) ((int4*)h)[i] = make_int4(0, 0, 0, 0);
}

__global__ __launch_bounds__(256) void hscatter(
    const uint4* __restrict__ xb4, const float* __restrict__ rel,
    const int* __restrict__ ei, const int* __restrict__ etype,
    const float* __restrict__ ew, float* __restrict__ h, int nE) {
  const int e = blockIdx.x * 16 + ((int)threadIdx.x >> 4);
  if (e >= nE) return;
  const int l = threadIdx.x & 15;
  const int s = ei[e], d = ei[nE + e], t = etype[e];
  const float wv = ew[e];
  const uint4 a = xb4[(size_t)s * 16 + l];
  const float4 r0 = ((const float4*)(rel + (size_t)t * D))[l * 2];
  const float4 r1 = ((const float4*)(rel + (size_t)t * D))[l * 2 + 1];
  float* o = h + (size_t)d * D + l * 8;
  atomicAdd(o + 0, wv * (bflo(a.x) - r0.x));
  atomicAdd(o + 1, wv * (bfhi(a.x) - r0.y));
  atomicAdd(o + 2, wv * (bflo(a.y) - r0.z));
  atomicAdd(o + 3, wv * (bfhi(a.y) - r0.w));
  atomicAdd(o + 4, wv * (bflo(a.z) - r1.x));
  atomicAdd(o + 5, wv * (bfhi(a.z) - r1.y));
  atomicAdd(o + 6, wv * (bflo(a.w) - r1.z));
  atomicAdd(o + 7, wv * (bfhi(a.w) - r1.w));
}

__global__ __launch_bounds__(256) void edge_scatter_f32(
    const float* __restrict__ x, const float* __restrict__ rel,
    const float* __restrict__ Wfwd,
    const int* __restrict__ ei, const int* __restrict__ etype,
    const float* __restrict__ ew, float* __restrict__ out, int nE) {
  __shared__ float msg[2][D];
  const int half = (int)threadIdx.x >> 7;
  const int c = threadIdx.x & 127;
  const int e = blockIdx.x * 2 + half;
  if (e >= nE) return;
  const int s = ei[e], d = ei[nE + e], t = etype[e];
  msg[half][c] = x[(size_t)s * D + c] - rel[(size_t)t * D + c];
  __syncthreads();
  float a = 0.f;
  #pragma unroll 8
  for (int k = 0; k < D; ++k) a += msg[half][k] * Wfwd[c * D + k];
  atomicAdd(&out[(size_t)d * D + c], ew[e] * a);
}

// ---------------------------------------------------------------------------
extern "C" void kernel_launch(void* const* d_in, const int* in_sizes, int n_in,
                              void* d_out, int out_size, void* d_ws, size_t ws_size,
                              hipStream_t stream) {
  const float* x      = (const float*)d_in[0];
  const int*   ei     = (const int*)d_in[1];
  const int*   etype  = (const int*)d_in[2];
  const float* rel    = (const float*)d_in[3];
  const float* ew     = (const float*)d_in[4];
  const float* Wself  = (const float*)d_in[5];
  const float* Wfwd   = (const float*)d_in[6];
  const float* Wrel   = (const float*)d_in[7];
  const float* bias   = (const float*)d_in[8];

  const int nN = in_sizes[0] / D;       // 100000
  const int nE = in_sizes[2];           // 625000
  const int nR = in_sizes[3] / D;       // 200

  float* out     = (float*)d_out;
  float* rel_out = (float*)d_out + (size_t)nN * D;

  // workspace carve-up (256B-aligned)
  char* w = (char*)d_ws;
  size_t off = 0;
  auto carve = [&](size_t bytes) {
    char* p = w + off;
    off = (off + bytes + 255) & ~(size_t)255;
    return p;
  };
  unsigned short* xb  = (unsigned short*)carve((size_t)nN * D * sizeof(unsigned short));
  unsigned short* Wb  = (unsigned short*)carve(2 * 8 * 4 * 512 * sizeof(unsigned short));
  int*   offs = (int*)carve((size_t)nN * sizeof(int));
  uint2* meta = (uint2*)carve((size_t)nE * sizeof(uint2));
  int*   bsum = (int*)carve(4096 * sizeof(int));
  const size_t need = off;

  const int* dst = ei + nE;
  const int nb = (nN + SCAN_B - 1) / SCAN_B;
  const int relBlocks  = (nR + 1) / 2;
  const int zeroBlocks = (nN + 1023) / 1024;
  const int xbBlocks   = (int)(((size_t)nN * D + 2047) / 2048);
  const int histBlocks = (nE + 1023) / 1024;
  const int aggBlocks  = (nN + NT - 1) / NT;

  const bool csr_ok = (need <= ws_size) && (nb <= 4096) &&
                      (nN < (1 << 20)) && (nR <= 4096);
  const bool fast_scan = (nb <= 512) && (nE < (1 << 30));
  const size_t hBytes = (size_t)nN * D * sizeof(float);
  const bool h_ok = ((size_t)nN * D * sizeof(unsigned short) + 256 + hBytes) <= ws_size;

  // K1: Wb prep + rel_out GEMV + zero offs/bsum (small)
  prep_kernel<<<16 + relBlocks + zeroBlocks, 256, 0, stream>>>(
      Wself, Wfwd, rel, Wrel, Wb, rel_out, offs, bsum, nR, nN, relBlocks, nb);

  if (csr_ok) {
    // K2: xb = bf16(x) streaming + dst histogram co-scheduled
    xb_hist<<<xbBlocks + histBlocks, 256, 0, stream>>>(
        x, xb, dst, offs, nN * D, nE, xbBlocks);
    // K3: exclusive scan (single-dispatch when co-residency is guaranteed)
    if (fast_scan) {
      scan_single<<<nb, 256, 0, stream>>>(offs, bsum, nN);
    } else {
      scan_pass1<<<nb, SCAN_B, 0, stream>>>(offs, bsum, nN);
      scan_pass3<<<nb, SCAN_B, 0, stream>>>(offs, bsum, nN);
    }
    // K4: CSR fill
    fill_kernel<<<(nE + 255) / 256, 256, 0, stream>>>(ei, dst, etype, ew, offs, meta, nE);
    // K5: fused aggregate + GEMM
    fused_ag<<<aggBlocks, 256, 0, stream>>>(
        xb, (const float4*)rel, meta, offs, Wb, bias, out,
        nN, 0, (const float*)0);
  } else if (h_ok) {
    xb_hist<<<xbBlocks, 256, 0, stream>>>(x, xb, dst, offs, nN * D, 0, xbBlocks);
    float* h = (float*)(w + (((size_t)nN * D * sizeof(unsigned short) + 255) & ~(size_t)255));
    const int n4 = (nN * D) / 4;
    hzero<<<(n4 + 255) / 256, 256, 0, stream>>>(h, n4);
    hscatter<<<(nE + 15) / 16, 256, 0, stream>>>(
        (const uint4*)xb, rel, ei, etype, ew, h, nE);
    fused_ag<<<aggBlocks, 256, 0, stream>>>(
        xb, (const float4*)rel, (const uint2*)0, (const int*)0,
        Wb, bias, out, nN, 1, h);
  } else {
    xb_hist<<<xbBlocks, 256, 0, stream>>>(x, xb, dst, offs, nN * D, 0, xbBlocks);
    fused_ag<<<aggBlocks, 256, 0, stream>>>(
        xb, (const float4*)rel, (const uint2*)0, (const int*)0,
        Wb, bias, out, nN, 1, (const float*)0);
    edge_scatter_f32<<<(nE + 1) / 2, 256, 0, stream>>>(
        x, rel, Wfwd, ei, etype, ew, out, nE);
  }
}

// Round 8
// 249.187 us; speedup vs baseline: 2.6578x; 1.0062x over previous
//
#include <hip/hip_runtime.h>

#define D 128
#define SCAN_B 256
#define NT 32            // nodes per fused_ag block
#define HPAD 132         // padded LDS row (floats) — breaks stride-128 bank alias

typedef short bf16x8 __attribute__((ext_vector_type(8)));
typedef float f32x4 __attribute__((ext_vector_type(4)));

static __device__ __forceinline__ unsigned short f2bf(float f) {
  union { float f; unsigned u; } v; v.f = f;
  return (unsigned short)((v.u + 0x7FFF + ((v.u >> 16) & 1)) >> 16);   // RNE
}
static __device__ __forceinline__ float bf2f(unsigned short h) {
  union { unsigned u; float f; } v; v.u = ((unsigned)h) << 16;
  return v.f;
}
static __device__ __forceinline__ float bflo(unsigned u) {
  union { unsigned u; float f; } v; v.u = u << 16; return v.f;
}
static __device__ __forceinline__ float bfhi(unsigned u) {
  union { unsigned u; float f; } v; v.u = u & 0xFFFF0000u; return v.f;
}

// ---------------------------------------------------------------------------
// K1 prep_xb_hist: ONE kernel = {Wb swizzle | rel_out GEMV | xb=bf16(x) |
// dst histogram}. offs/bsum are pre-zeroed by a stream-ordered
// hipMemsetAsync, so the histogram needs no intra-grid ordering. The
// atomic-latency-bound hist blocks hide under 77MB of streaming traffic.
// ---------------------------------------------------------------------------
__global__ __launch_bounds__(256) void prep_xb_hist(
    const float* __restrict__ Wself, const float* __restrict__ Wfwd,
    const float* __restrict__ rel, const float* __restrict__ Wr,
    const float* __restrict__ x, unsigned short* __restrict__ xb,
    unsigned short* __restrict__ Wb, float* __restrict__ rel_out,
    const int* __restrict__ dst, int* __restrict__ offs,
    int nR, int nN, int nE, int relBlocks, int xbBlocks) {
  const int tid = threadIdx.x;
  const int bid = (int)blockIdx.x;
  if (bid < 16) {
    // Wb[frag*512 + lane*8 + j]: frag=((mat*8+ct)*4+kt); lane(q=lane>>4,r=lane&15)
    // holds W[ct*16+r][kt*32+q*8+j].  mat0=Wself, mat1=Wfwd.
    const int g = bid * 256 + tid;     // 0..4095
    const int frag = g >> 6, lane = g & 63;
    const int mat = frag >> 5, ct = (frag >> 2) & 7, kt = frag & 3;
    const int q = lane >> 4, r = lane & 15;
    const float* W = mat ? Wfwd : Wself;
    const float* src = W + (ct * 16 + r) * D + kt * 32 + q * 8;
    unsigned short* dstp = Wb + frag * 512 + lane * 8;
    #pragma unroll
    for (int j = 0; j < 8; ++j) dstp[j] = f2bf(src[j]);
  } else if (bid < 16 + relBlocks) {
    __shared__ float row[2][D];
    const int half = tid >> 7;                 // 0/1: which rel row
    const int c = tid & 127;
    const int rr = (bid - 16) * 2 + half;
    const int r2 = (rr < nR) ? rr : nR - 1;
    row[half][c] = rel[r2 * D + c];
    __syncthreads();
    const float4* xr4 = (const float4*)row[half];
    const float4* Wr4 = (const float4*)(Wr + c * D);
    float ar = 0.f;
    #pragma unroll 8
    for (int k4 = 0; k4 < 32; ++k4) {
      const float4 xv = xr4[k4];
      const float4 wr = Wr4[k4];
      ar += xv.x * wr.x + xv.y * wr.y + xv.z * wr.z + xv.w * wr.w;
    }
    if (rr < nR) rel_out[rr * D + c] = ar;
  } else if (bid < 16 + relBlocks + xbBlocks) {
    const int nElems = nN * D;
    const int i = ((bid - 16 - relBlocks) * 256 + tid) * 8;
    if (i + 7 < nElems) {
      const float4 u0 = *(const float4*)(x + i);
      const float4 u1 = *(const float4*)(x + i + 4);
      const unsigned p0 = (unsigned)f2bf(u0.x) | ((unsigned)f2bf(u0.y) << 16);
      const unsigned p1 = (unsigned)f2bf(u0.z) | ((unsigned)f2bf(u0.w) << 16);
      const unsigned p2 = (unsigned)f2bf(u1.x) | ((unsigned)f2bf(u1.y) << 16);
      const unsigned p3 = (unsigned)f2bf(u1.z) | ((unsigned)f2bf(u1.w) << 16);
      *(int4*)(xb + i) = make_int4((int)p0, (int)p1, (int)p2, (int)p3);
    } else {
      for (int k = i; k < nElems; ++k) xb[k] = f2bf(x[k]);
    }
  } else {
    const int i0 = ((bid - 16 - relBlocks - xbBlocks) * 256 + tid) * 4;
    if (i0 + 3 < nE) {
      const int4 d4 = *(const int4*)(dst + i0);
      atomicAdd(&offs[d4.x], 1); atomicAdd(&offs[d4.y], 1);
      atomicAdd(&offs[d4.z], 1); atomicAdd(&offs[d4.w], 1);
    } else {
      for (int e = i0; e < nE && e < i0 + 4; ++e) atomicAdd(&offs[dst[e]], 1);
    }
  }
}

// ---------------------------------------------------------------------------
// scan_single: ONE-dispatch exclusive scan via decoupled-lookback AGGREGATES.
//  Each block: local inclusive scan -> publish (total<<1)|1 into agg[b]
//  (data+ready packed in one word: no fence needed) -> sum all predecessors'
//  published aggregates (parallel spins, no serial chain) -> write exclusive.
//  SAFETY: host only uses this when nb <= 512 (co-residency guaranteed by
//  __launch_bounds__(256,2) x 256 CU); publish happens BEFORE any spin.
//  Totals must fit 31 bits (nE < 2^30) — host guard.
// ---------------------------------------------------------------------------
__global__ __launch_bounds__(256, 2) void scan_single(
    int* __restrict__ deg_offs, int* __restrict__ agg, int n) {
  __shared__ int sd[256];
  __shared__ int sp[256];
  __shared__ int boffs;
  const int t = threadIdx.x;
  const int b = (int)blockIdx.x;
  const int i = b * 256 + t;
  const int v = (i < n) ? deg_offs[i] : 0;
  sd[t] = v;
  __syncthreads();
  for (int off = 1; off < 256; off <<= 1) {
    const int add = (t >= off) ? sd[t - off] : 0;
    __syncthreads();
    sd[t] += add;
    __syncthreads();
  }
  if (t == 0) atomicExch(&agg[b], (sd[255] << 1) | 1);   // publish FIRST
  int partial = 0;
  for (int j = t; j < b; j += 256) {
    int a;
    while (((a = atomicOr(&agg[j], 0)) & 1) == 0) __builtin_amdgcn_s_sleep(4);
    partial += (a >> 1);
  }
  sp[t] = partial;
  __syncthreads();
  for (int s = 128; s > 0; s >>= 1) {
    if (t < s) sp[t] += sp[t + s];
    __syncthreads();
  }
  if (t == 0) boffs = sp[0];
  __syncthreads();
  if (i < n) deg_offs[i] = sd[t] - v + boffs;   // exclusive global
}

// ---------------------------------------------------------------------------
// Fallback two-kernel scan (nb > 512)
// ---------------------------------------------------------------------------
__global__ __launch_bounds__(SCAN_B) void scan_pass1(
    const int* __restrict__ deg, int* __restrict__ bsum, int n) {
  __shared__ int sd[SCAN_B];
  const int i = blockIdx.x * SCAN_B + threadIdx.x;
  sd[threadIdx.x] = (i < n) ? deg[i] : 0;
  __syncthreads();
  for (int s = SCAN_B / 2; s > 0; s >>= 1) {
    if (threadIdx.x < s) sd[threadIdx.x] += sd[threadIdx.x + s];
    __syncthreads();
  }
  if (threadIdx.x == 0) bsum[blockIdx.x] = sd[0];
}

__global__ __launch_bounds__(SCAN_B) void scan_pass3(
    int* __restrict__ deg_offs, const int* __restrict__ bsum, int n) {
  __shared__ int sd[SCAN_B];
  __shared__ int boffs;
  const int t = threadIdx.x;
  int partial = 0;
  for (int j = t; j < (int)blockIdx.x; j += SCAN_B) partial += bsum[j];
  sd[t] = partial;
  __syncthreads();
  for (int s = SCAN_B / 2; s > 0; s >>= 1) {
    if (t < s) sd[t] += sd[t + s];
    __syncthreads();
  }
  if (t == 0) boffs = sd[0];
  __syncthreads();
  const int i = blockIdx.x * SCAN_B + t;
  const int v = (i < n) ? deg_offs[i] : 0;
  sd[t] = v;
  __syncthreads();
  for (int off = 1; off < SCAN_B; off <<= 1) {
    const int add = (t >= off) ? sd[t - off] : 0;
    __syncthreads();
    sd[t] += add;
    __syncthreads();
  }
  if (i < n) deg_offs[i] = sd[t] - v + boffs;
}

// ---------------------------------------------------------------------------
// fill: CSR-ordered PACKED metadata. meta[p] = {src | et<<20, bits(ew)}.
// After this, offs[n] == end of bucket n (cursor advanced to end).
// ---------------------------------------------------------------------------
__global__ void fill_kernel(const int* __restrict__ src, const int* __restrict__ dstv,
                            const int* __restrict__ et, const float* __restrict__ ew,
                            int* __restrict__ cursor, uint2* __restrict__ meta, int nE) {
  const int e = blockIdx.x * blockDim.x + threadIdx.x;
  if (e < nE) {
    const int p = atomicAdd(&cursor[dstv[e]], 1);
    meta[p] = make_uint2((unsigned)src[e] | ((unsigned)et[e] << 20),
                         __float_as_uint(ew[e]));
  }
}

// ---------------------------------------------------------------------------
// fused_ag (R5 pair version — measured 64us): aggregate-then-project,
//  h in LDS only. 32 lanes/node, group owns node, straight-line PAIR
//  inner loop (depth-2 MLP fits the compiler's 32-VGPR choice; quad
//  regressed, R7). (256,8): 8 blocks/CU (17.4KB LDS).
//  GEMM: 4 waves = (row-half, col-half); acc = x@Ws + hi@Wf + lo@Wf.
// ---------------------------------------------------------------------------
__global__ __launch_bounds__(256, 8) void fused_ag(
    const unsigned short* __restrict__ xb, const float4* __restrict__ rel4,
    const uint2* __restrict__ meta, const int* __restrict__ offs,
    const unsigned short* __restrict__ Wb, const float* __restrict__ bias,
    float* __restrict__ out,
    int nN, int useGlobalH, const float* __restrict__ hg) {
  __shared__ float hsm[NT][HPAD];
  __shared__ int bndv[NT + 1];
  const int tid = threadIdx.x;
  const int g0 = blockIdx.x * NT;
  const uint2* xb2 = (const uint2*)xb;

  if (!useGlobalH) {
    if (tid <= NT) {
      int v;
      if (tid == 0) v = (g0 == 0) ? 0 : offs[g0 - 1];
      else { int idx = g0 + tid - 1; if (idx > nN - 1) idx = nN - 1; v = offs[idx]; }
      bndv[tid] = v;
    }
    __syncthreads();

    const int g = tid >> 5;          // group 0..7
    const int l32 = tid & 31;
    #pragma unroll
    for (int r = 0; r < NT / 8; ++r) {
      const int nl = r * 8 + g;
      const int n = g0 + nl;
      if (n < nN) {
        float a0 = 0.f, a1 = 0.f, a2 = 0.f, a3 = 0.f;
        const int start = bndv[nl], end = bndv[nl + 1];
        for (int base = start; base < end; base += 32) {
          const int m = (end - base < 32) ? (end - base) : 32;
          uint2 mv = make_uint2(0u, 0u);
          if (l32 < m) mv = meta[base + l32];
          int jb = 0;
          for (; jb + 2 <= m; jb += 2) {
            // two edges, branch-free: issue all 4 gathers, then consume
            const unsigned pkA = (unsigned)__shfl((int)mv.x, jb, 32);
            const float wA = __uint_as_float(__shfl((int)mv.y, jb, 32));
            const unsigned pkB = (unsigned)__shfl((int)mv.x, jb + 1, 32);
            const float wB = __uint_as_float(__shfl((int)mv.y, jb + 1, 32));
            const uint2 avA = xb2[(size_t)(pkA & 0xFFFFFu) * 32 + l32];
            const float4 rA = rel4[(size_t)(pkA >> 20) * 32 + l32];
            const uint2 avB = xb2[(size_t)(pkB & 0xFFFFFu) * 32 + l32];
            const float4 rB = rel4[(size_t)(pkB >> 20) * 32 + l32];
            a0 += wA * (bflo(avA.x) - rA.x);
            a1 += wA * (bfhi(avA.x) - rA.y);
            a2 += wA * (bflo(avA.y) - rA.z);
            a3 += wA * (bfhi(avA.y) - rA.w);
            a0 += wB * (bflo(avB.x) - rB.x);
            a1 += wB * (bfhi(avB.x) - rB.y);
            a2 += wB * (bflo(avB.y) - rB.z);
            a3 += wB * (bfhi(avB.y) - rB.w);
          }
          if (jb < m) {
            const unsigned pk = (unsigned)__shfl((int)mv.x, jb, 32);
            const float wv = __uint_as_float(__shfl((int)mv.y, jb, 32));
            const uint2 av = xb2[(size_t)(pk & 0xFFFFFu) * 32 + l32];
            const float4 rv = rel4[(size_t)(pk >> 20) * 32 + l32];
            a0 += wv * (bflo(av.x) - rv.x);
            a1 += wv * (bfhi(av.x) - rv.y);
            a2 += wv * (bflo(av.y) - rv.z);
            a3 += wv * (bfhi(av.y) - rv.w);
          }
        }
        *(float4*)&hsm[nl][l32 * 4] = make_float4(a0, a1, a2, a3);
      }
    }
  } else {
    for (int idx = tid; idx < NT * 32; idx += 256) {
      const int rr = idx >> 5, cc = (idx & 31) * 4;
      const int n = g0 + rr;
      float4 v = make_float4(0.f, 0.f, 0.f, 0.f);
      if (n < nN && hg) v = *(const float4*)(hg + (size_t)n * D + cc);
      *(float4*)&hsm[rr][cc] = v;
    }
  }
  __syncthreads();

  // ---- GEMM phase: wave w = (row-half w>>1, col-half w&1) -------------
  const int w = tid >> 6, lane = tid & 63;
  const int q = lane >> 4, r = lane & 15;
  const int rowbase = (w >> 1) * 16;
  const int ch = w & 1;
  const int lr = rowbase + r;
  int grow = g0 + lr; if (grow >= nN) grow = nN - 1;

  f32x4 acc[4];
  #pragma unroll
  for (int c2 = 0; c2 < 4; ++c2) acc[c2] = (f32x4)0.f;

  #pragma unroll
  for (int kt = 0; kt < 4; ++kt) {
    const bf16x8 xa = *(const bf16x8*)(xb + (size_t)grow * D + kt * 32 + q * 8);
    const float* hp = &hsm[lr][kt * 32 + q * 8];
    const float4 h0 = *(const float4*)hp;
    const float4 h1 = *(const float4*)(hp + 4);
    const float hv[8] = {h0.x, h0.y, h0.z, h0.w, h1.x, h1.y, h1.z, h1.w};
    bf16x8 hi, lo;
    #pragma unroll
    for (int j = 0; j < 8; ++j) {
      const unsigned short hb = f2bf(hv[j]);
      hi[j] = (short)hb;
      lo[j] = (short)f2bf(hv[j] - bf2f(hb));
    }
    #pragma unroll
    for (int c2 = 0; c2 < 4; ++c2) {
      const int ct = ch * 4 + c2;
      const bf16x8 bS = *(const bf16x8*)(Wb + ((0 * 8 + ct) * 4 + kt) * 512 + lane * 8);
      const bf16x8 bF = *(const bf16x8*)(Wb + ((1 * 8 + ct) * 4 + kt) * 512 + lane * 8);
      acc[c2] = __builtin_amdgcn_mfma_f32_16x16x32_bf16(xa, bS, acc[c2], 0, 0, 0);
      acc[c2] = __builtin_amdgcn_mfma_f32_16x16x32_bf16(hi, bF, acc[c2], 0, 0, 0);
      acc[c2] = __builtin_amdgcn_mfma_f32_16x16x32_bf16(lo, bF, acc[c2], 0, 0, 0);
    }
  }

  #pragma unroll
  for (int c2 = 0; c2 < 4; ++c2) {
    const int col = ch * 64 + c2 * 16 + r;
    const float bv = bias[col];
    #pragma unroll
    for (int reg = 0; reg < 4; ++reg) {
      const int row = g0 + rowbase + q * 4 + reg;
      if (row < nN) out[(size_t)row * D + col] = acc[c2][reg] + bv;
    }
  }
}

// ---------------------------------------------------------------------------
// Fallbacks (never taken at harness sizes)
// ---------------------------------------------------------------------------
__global__ __launch_bounds__(256) void hzero(float* __restrict__ h, int n4) {
  const int i = blockIdx.x * 256 + threadIdx.x;
  if (i < n4) ((int4*)h)[i] = make_int4(0, 0, 0, 0);
}

__global__ __launch_bounds__(256) void hscatter(
    const uint4* __restrict__ xb4, const float* __restrict__ rel,
    const int* __restrict__ ei, const int* __restrict__ etype,
    const float* __restrict__ ew, float* __restrict__ h, int nE) {
  const int e = blockIdx.x * 16 + ((int)threadIdx.x >> 4);
  if (e >= nE) return;
  const int l = threadIdx.x & 15;
  const int s = ei[e], d = ei[nE + e], t = etype[e];
  const float wv = ew[e];
  const uint4 a = xb4[(size_t)s * 16 + l];
  const float4 r0 = ((const float4*)(rel + (size_t)t * D))[l * 2];
  const float4 r1 = ((const float4*)(rel + (size_t)t * D))[l * 2 + 1];
  float* o = h + (size_t)d * D + l * 8;
  atomicAdd(o + 0, wv * (bflo(a.x) - r0.x));
  atomicAdd(o + 1, wv * (bfhi(a.x) - r0.y));
  atomicAdd(o + 2, wv * (bflo(a.y) - r0.z));
  atomicAdd(o + 3, wv * (bfhi(a.y) - r0.w));
  atomicAdd(o + 4, wv * (bflo(a.z) - r1.x));
  atomicAdd(o + 5, wv * (bfhi(a.z) - r1.y));
  atomicAdd(o + 6, wv * (bflo(a.w) - r1.z));
  atomicAdd(o + 7, wv * (bfhi(a.w) - r1.w));
}

__global__ __launch_bounds__(256) void edge_scatter_f32(
    const float* __restrict__ x, const float* __restrict__ rel,
    const float* __restrict__ Wfwd,
    const int* __restrict__ ei, const int* __restrict__ etype,
    const float* __restrict__ ew, float* __restrict__ out, int nE) {
  __shared__ float msg[2][D];
  const int half = (int)threadIdx.x >> 7;
  const int c = threadIdx.x & 127;
  const int e = blockIdx.x * 2 + half;
  if (e >= nE) return;
  const int s = ei[e], d = ei[nE + e], t = etype[e];
  msg[half][c] = x[(size_t)s * D + c] - rel[(size_t)t * D + c];
  __syncthreads();
  float a = 0.f;
  #pragma unroll 8
  for (int k = 0; k < D; ++k) a += msg[half][k] * Wfwd[c * D + k];
  atomicAdd(&out[(size_t)d * D + c], ew[e] * a);
}

// ---------------------------------------------------------------------------
extern "C" void kernel_launch(void* const* d_in, const int* in_sizes, int n_in,
                              void* d_out, int out_size, void* d_ws, size_t ws_size,
                              hipStream_t stream) {
  const float* x      = (const float*)d_in[0];
  const int*   ei     = (const int*)d_in[1];
  const int*   etype  = (const int*)d_in[2];
  const float* rel    = (const float*)d_in[3];
  const float* ew     = (const float*)d_in[4];
  const float* Wself  = (const float*)d_in[5];
  const float* Wfwd   = (const float*)d_in[6];
  const float* Wrel   = (const float*)d_in[7];
  const float* bias   = (const float*)d_in[8];

  const int nN = in_sizes[0] / D;       // 100000
  const int nE = in_sizes[2];           // 625000
  const int nR = in_sizes[3] / D;       // 200

  float* out     = (float*)d_out;
  float* rel_out = (float*)d_out + (size_t)nN * D;

  // workspace carve-up (256B-aligned). offs and bsum adjacent => ONE memset.
  char* w = (char*)d_ws;
  size_t off = 0;
  auto carve = [&](size_t bytes) {
    char* p = w + off;
    off = (off + bytes + 255) & ~(size_t)255;
    return p;
  };
  unsigned short* xb  = (unsigned short*)carve((size_t)nN * D * sizeof(unsigned short));
  unsigned short* Wb  = (unsigned short*)carve(2 * 8 * 4 * 512 * sizeof(unsigned short));
  int*   offs = (int*)carve((size_t)nN * sizeof(int));
  int*   bsum = (int*)carve(4096 * sizeof(int));
  uint2* meta = (uint2*)carve((size_t)nE * sizeof(uint2));
  const size_t need = off;
  const size_t zeroSpan = (size_t)((char*)(bsum + 4096) - (char*)offs);

  const int* dst = ei + nE;
  const int nb = (nN + SCAN_B - 1) / SCAN_B;
  const int relBlocks  = (nR + 1) / 2;
  const int xbBlocks   = (int)(((size_t)nN * D + 2047) / 2048);
  const int histBlocks = (nE + 1023) / 1024;
  const int aggBlocks  = (nN + NT - 1) / NT;

  const bool csr_ok = (need <= ws_size) && (nb <= 4096) &&
                      (nN < (1 << 20)) && (nR <= 4096);
  const bool fast_scan = (nb <= 512) && (nE < (1 << 30));
  const size_t hBytes = (size_t)nN * D * sizeof(float);
  const bool h_ok = ((size_t)nN * D * sizeof(unsigned short) + 256 + hBytes) <= ws_size;

  if (csr_ok) {
    // D0: zero offs+bsum via SDMA (stream-ordered, graph-capture safe)
    (void)hipMemsetAsync(offs, 0, zeroSpan, stream);
    // K1: Wb + rel_out + xb + histogram (hist hidden under streaming)
    prep_xb_hist<<<16 + relBlocks + xbBlocks + histBlocks, 256, 0, stream>>>(
        Wself, Wfwd, rel, Wrel, x, xb, Wb, rel_out, dst, offs,
        nR, nN, nE, relBlocks, xbBlocks);
    // K2: exclusive scan (single-dispatch when co-residency guaranteed)
    if (fast_scan) {
      scan_single<<<nb, 256, 0, stream>>>(offs, bsum, nN);
    } else {
      scan_pass1<<<nb, SCAN_B, 0, stream>>>(offs, bsum, nN);
      scan_pass3<<<nb, SCAN_B, 0, stream>>>(offs, bsum, nN);
    }
    // K3: CSR fill
    fill_kernel<<<(nE + 255) / 256, 256, 0, stream>>>(ei, dst, etype, ew, offs, meta, nE);
    // K4: fused aggregate + GEMM
    fused_ag<<<aggBlocks, 256, 0, stream>>>(
        xb, (const float4*)rel, meta, offs, Wb, bias, out,
        nN, 0, (const float*)0);
  } else if (h_ok) {
    prep_xb_hist<<<16 + relBlocks + xbBlocks, 256, 0, stream>>>(
        Wself, Wfwd, rel, Wrel, x, xb, Wb, rel_out, dst, (int*)0,
        nR, nN, 0, relBlocks, xbBlocks);
    float* h = (float*)(w + (((size_t)nN * D * sizeof(unsigned short) + 255) & ~(size_t)255));
    const int n4 = (nN * D) / 4;
    hzero<<<(n4 + 255) / 256, 256, 0, stream>>>(h, n4);
    hscatter<<<(nE + 15) / 16, 256, 0, stream>>>(
        (const uint4*)xb, rel, ei, etype, ew, h, nE);
    fused_ag<<<aggBlocks, 256, 0, stream>>>(
        xb, (const float4*)rel, (const uint2*)0, (const int*)0,
        Wb, bias, out, nN, 1, h);
  } else {
    prep_xb_hist<<<16 + relBlocks + xbBlocks, 256, 0, stream>>>(
        Wself, Wfwd, rel, Wrel, x, xb, Wb, rel_out, dst, (int*)0,
        nR, nN, 0, relBlocks, xbBlocks);
    fused_ag<<<aggBlocks, 256, 0, stream>>>(
        xb, (const float4*)rel, (const uint2*)0, (const int*)0,
        Wb, bias, out, nN, 1, (const float*)0);
    edge_scatter_f32<<<(nE + 1) / 2, 256, 0, stream>>>(
        x, rel, Wfwd, ei, etype, ew, out, nE);
  }
}

// Round 9
// 242.370 us; speedup vs baseline: 2.7325x; 1.0281x over previous
//
#include <hip/hip_runtime.h>

#define D 128
#define SCAN_B 256
#define NT 32            // nodes per fused_ag block
#define HPAD 132         // padded LDS row (floats) — breaks stride-128 bank alias

typedef short bf16x8 __attribute__((ext_vector_type(8)));
typedef float f32x4 __attribute__((ext_vector_type(4)));

static __device__ __forceinline__ unsigned short f2bf(float f) {
  union { float f; unsigned u; } v; v.f = f;
  return (unsigned short)((v.u + 0x7FFF + ((v.u >> 16) & 1)) >> 16);   // RNE
}
static __device__ __forceinline__ float bf2f(unsigned short h) {
  union { unsigned u; float f; } v; v.u = ((unsigned)h) << 16;
  return v.f;
}
static __device__ __forceinline__ float bflo(unsigned u) {
  union { unsigned u; float f; } v; v.u = u << 16; return v.f;
}
static __device__ __forceinline__ float bfhi(unsigned u) {
  union { unsigned u; float f; } v; v.u = u & 0xFFFF0000u; return v.f;
}

// ---------------------------------------------------------------------------
// K1 prep_xb_hist: ONE kernel = {Wb swizzle | rel_out GEMV | rfb=bf16(rel) |
// xb=bf16(x) | dst histogram}. offs/bsum pre-zeroed by hipMemsetAsync.
// ---------------------------------------------------------------------------
__global__ __launch_bounds__(256) void prep_xb_hist(
    const float* __restrict__ Wself, const float* __restrict__ Wfwd,
    const float* __restrict__ rel, const float* __restrict__ Wr,
    const float* __restrict__ x, unsigned short* __restrict__ xb,
    unsigned short* __restrict__ rfb, unsigned short* __restrict__ Wb,
    float* __restrict__ rel_out, const int* __restrict__ dst,
    int* __restrict__ offs,
    int nR, int nN, int nE, int relBlocks, int rfbBlocks, int xbBlocks) {
  const int tid = threadIdx.x;
  const int bid = (int)blockIdx.x;
  if (bid < 16) {
    // Wb[frag*512 + lane*8 + j]: frag=((mat*8+ct)*4+kt); lane(q=lane>>4,r=lane&15)
    // holds W[ct*16+r][kt*32+q*8+j].  mat0=Wself, mat1=Wfwd.
    const int g = bid * 256 + tid;     // 0..4095
    const int frag = g >> 6, lane = g & 63;
    const int mat = frag >> 5, ct = (frag >> 2) & 7, kt = frag & 3;
    const int q = lane >> 4, r = lane & 15;
    const float* W = mat ? Wfwd : Wself;
    const float* src = W + (ct * 16 + r) * D + kt * 32 + q * 8;
    unsigned short* dstp = Wb + frag * 512 + lane * 8;
    #pragma unroll
    for (int j = 0; j < 8; ++j) dstp[j] = f2bf(src[j]);
  } else if (bid < 16 + relBlocks) {
    __shared__ float row[2][D];
    const int half = tid >> 7;                 // 0/1: which rel row
    const int c = tid & 127;
    const int rr = (bid - 16) * 2 + half;
    const int r2 = (rr < nR) ? rr : nR - 1;
    row[half][c] = rel[r2 * D + c];
    __syncthreads();
    const float4* xr4 = (const float4*)row[half];
    const float4* Wr4 = (const float4*)(Wr + c * D);
    float ar = 0.f;
    #pragma unroll 8
    for (int k4 = 0; k4 < 32; ++k4) {
      const float4 xv = xr4[k4];
      const float4 wr = Wr4[k4];
      ar += xv.x * wr.x + xv.y * wr.y + xv.z * wr.z + xv.w * wr.w;
    }
    if (rr < nR) rel_out[rr * D + c] = ar;
  } else if (bid < 16 + relBlocks + rfbBlocks) {
    const int nElems = nR * D;
    const int i = ((bid - 16 - relBlocks) * 256 + tid) * 8;
    if (i + 7 < nElems) {
      const float4 u0 = *(const float4*)(rel + i);
      const float4 u1 = *(const float4*)(rel + i + 4);
      const unsigned p0 = (unsigned)f2bf(u0.x) | ((unsigned)f2bf(u0.y) << 16);
      const unsigned p1 = (unsigned)f2bf(u0.z) | ((unsigned)f2bf(u0.w) << 16);
      const unsigned p2 = (unsigned)f2bf(u1.x) | ((unsigned)f2bf(u1.y) << 16);
      const unsigned p3 = (unsigned)f2bf(u1.z) | ((unsigned)f2bf(u1.w) << 16);
      *(int4*)(rfb + i) = make_int4((int)p0, (int)p1, (int)p2, (int)p3);
    } else {
      for (int k = i; k < nElems; ++k) rfb[k] = f2bf(rel[k]);
    }
  } else if (bid < 16 + relBlocks + rfbBlocks + xbBlocks) {
    const int nElems = nN * D;
    const int i = ((bid - 16 - relBlocks - rfbBlocks) * 256 + tid) * 8;
    if (i + 7 < nElems) {
      const float4 u0 = *(const float4*)(x + i);
      const float4 u1 = *(const float4*)(x + i + 4);
      const unsigned p0 = (unsigned)f2bf(u0.x) | ((unsigned)f2bf(u0.y) << 16);
      const unsigned p1 = (unsigned)f2bf(u0.z) | ((unsigned)f2bf(u0.w) << 16);
      const unsigned p2 = (unsigned)f2bf(u1.x) | ((unsigned)f2bf(u1.y) << 16);
      const unsigned p3 = (unsigned)f2bf(u1.z) | ((unsigned)f2bf(u1.w) << 16);
      *(int4*)(xb + i) = make_int4((int)p0, (int)p1, (int)p2, (int)p3);
    } else {
      for (int k = i; k < nElems; ++k) xb[k] = f2bf(x[k]);
    }
  } else {
    const int i0 = ((bid - 16 - relBlocks - rfbBlocks - xbBlocks) * 256 + tid) * 4;
    if (i0 + 3 < nE) {
      const int4 d4 = *(const int4*)(dst + i0);
      atomicAdd(&offs[d4.x], 1); atomicAdd(&offs[d4.y], 1);
      atomicAdd(&offs[d4.z], 1); atomicAdd(&offs[d4.w], 1);
    } else {
      for (int e = i0; e < nE && e < i0 + 4; ++e) atomicAdd(&offs[dst[e]], 1);
    }
  }
}

// ---------------------------------------------------------------------------
// scan_single: ONE-dispatch exclusive scan via decoupled-lookback AGGREGATES.
//  publish (total<<1)|1 (data+ready in one word), spin-read predecessors in
//  parallel. Host uses only when nb <= 512 (co-residency via (256,2)) and
//  nE < 2^30.
// ---------------------------------------------------------------------------
__global__ __launch_bounds__(256, 2) void scan_single(
    int* __restrict__ deg_offs, int* __restrict__ agg, int n) {
  __shared__ int sd[256];
  __shared__ int sp[256];
  __shared__ int boffs;
  const int t = threadIdx.x;
  const int b = (int)blockIdx.x;
  const int i = b * 256 + t;
  const int v = (i < n) ? deg_offs[i] : 0;
  sd[t] = v;
  __syncthreads();
  for (int off = 1; off < 256; off <<= 1) {
    const int add = (t >= off) ? sd[t - off] : 0;
    __syncthreads();
    sd[t] += add;
    __syncthreads();
  }
  if (t == 0) atomicExch(&agg[b], (sd[255] << 1) | 1);   // publish FIRST
  int partial = 0;
  for (int j = t; j < b; j += 256) {
    int a;
    while (((a = atomicOr(&agg[j], 0)) & 1) == 0) __builtin_amdgcn_s_sleep(4);
    partial += (a >> 1);
  }
  sp[t] = partial;
  __syncthreads();
  for (int s = 128; s > 0; s >>= 1) {
    if (t < s) sp[t] += sp[t + s];
    __syncthreads();
  }
  if (t == 0) boffs = sp[0];
  __syncthreads();
  if (i < n) deg_offs[i] = sd[t] - v + boffs;   // exclusive global
}

// ---------------------------------------------------------------------------
// Fallback two-kernel scan (nb > 512)
// ---------------------------------------------------------------------------
__global__ __launch_bounds__(SCAN_B) void scan_pass1(
    const int* __restrict__ deg, int* __restrict__ bsum, int n) {
  __shared__ int sd[SCAN_B];
  const int i = blockIdx.x * SCAN_B + threadIdx.x;
  sd[threadIdx.x] = (i < n) ? deg[i] : 0;
  __syncthreads();
  for (int s = SCAN_B / 2; s > 0; s >>= 1) {
    if (threadIdx.x < s) sd[threadIdx.x] += sd[threadIdx.x + s];
    __syncthreads();
  }
  if (threadIdx.x == 0) bsum[blockIdx.x] = sd[0];
}

__global__ __launch_bounds__(SCAN_B) void scan_pass3(
    int* __restrict__ deg_offs, const int* __restrict__ bsum, int n) {
  __shared__ int sd[SCAN_B];
  __shared__ int boffs;
  const int t = threadIdx.x;
  int partial = 0;
  for (int j = t; j < (int)blockIdx.x; j += SCAN_B) partial += bsum[j];
  sd[t] = partial;
  __syncthreads();
  for (int s = SCAN_B / 2; s > 0; s >>= 1) {
    if (t < s) sd[t] += sd[t + s];
    __syncthreads();
  }
  if (t == 0) boffs = sd[0];
  __syncthreads();
  const int i = blockIdx.x * SCAN_B + t;
  const int v = (i < n) ? deg_offs[i] : 0;
  sd[t] = v;
  __syncthreads();
  for (int off = 1; off < SCAN_B; off <<= 1) {
    const int add = (t >= off) ? sd[t - off] : 0;
    __syncthreads();
    sd[t] += add;
    __syncthreads();
  }
  if (i < n) deg_offs[i] = sd[t] - v + boffs;
}

// ---------------------------------------------------------------------------
// fill: CSR-ordered PACKED metadata. meta[p] = {src | et<<20, bits(ew)}.
// After this, offs[n] == end of bucket n (cursor advanced to end).
// ---------------------------------------------------------------------------
__global__ void fill_kernel(const int* __restrict__ src, const int* __restrict__ dstv,
                            const int* __restrict__ et, const float* __restrict__ ew,
                            int* __restrict__ cursor, uint2* __restrict__ meta, int nE) {
  const int e = blockIdx.x * blockDim.x + threadIdx.x;
  if (e < nE) {
    const int p = atomicAdd(&cursor[dstv[e]], 1);
    meta[p] = make_uint2((unsigned)src[e] | ((unsigned)et[e] << 20),
                         __float_as_uint(ew[e]));
  }
}

// ---------------------------------------------------------------------------
// fused_ag v6: aggregate-then-project, h in LDS only.
//  Agg: 32 lanes/node; DYNAMIC group->node assignment via LDS cursor
//  (fixes intra-block degree imbalance: static 4-round mapping made the
//  block wait on its unluckiest group). Straight-line PAIR inner loop
//  (depth-2 MLP, the proven 64us structure) untouched. rel gathered as
//  bf16 (rfb, uint2 — halves rel bytes, R0-proven precision).
//  (256,8): 8 blocks/CU (17.4KB LDS).
//  GEMM: 4 waves = (row-half, col-half); acc = x@Ws + hi@Wf + lo@Wf.
// ---------------------------------------------------------------------------
__global__ __launch_bounds__(256, 8) void fused_ag(
    const unsigned short* __restrict__ xb, const unsigned short* __restrict__ rfb,
    const uint2* __restrict__ meta, const int* __restrict__ offs,
    const unsigned short* __restrict__ Wb, const float* __restrict__ bias,
    float* __restrict__ out,
    int nN, int useGlobalH, const float* __restrict__ hg) {
  __shared__ float hsm[NT][HPAD];
  __shared__ int bndv[NT + 1];
  __shared__ int curs;
  const int tid = threadIdx.x;
  const int g0 = blockIdx.x * NT;
  const uint2* xb2 = (const uint2*)xb;
  const uint2* rf2 = (const uint2*)rfb;

  if (!useGlobalH) {
    if (tid == 0) curs = 0;
    if (tid <= NT) {
      int v;
      if (tid == 0) v = (g0 == 0) ? 0 : offs[g0 - 1];
      else { int idx = g0 + tid - 1; if (idx > nN - 1) idx = nN - 1; v = offs[idx]; }
      bndv[tid] = v;
    }
    __syncthreads();

    const int l32 = tid & 31;
    for (;;) {
      int nl;
      if (l32 == 0) nl = atomicAdd(&curs, 1);
      nl = __shfl(nl, 0, 32);
      if (nl >= NT) break;
      const int n = g0 + nl;
      if (n >= nN) continue;
      float a0 = 0.f, a1 = 0.f, a2 = 0.f, a3 = 0.f;
      const int start = bndv[nl], end = bndv[nl + 1];
      for (int base = start; base < end; base += 32) {
        const int m = (end - base < 32) ? (end - base) : 32;
        uint2 mv = make_uint2(0u, 0u);
        if (l32 < m) mv = meta[base + l32];
        int jb = 0;
        for (; jb + 2 <= m; jb += 2) {
          // two edges, branch-free: issue all 4 gathers, then consume
          const unsigned pkA = (unsigned)__shfl((int)mv.x, jb, 32);
          const float wA = __uint_as_float(__shfl((int)mv.y, jb, 32));
          const unsigned pkB = (unsigned)__shfl((int)mv.x, jb + 1, 32);
          const float wB = __uint_as_float(__shfl((int)mv.y, jb + 1, 32));
          const uint2 avA = xb2[(size_t)(pkA & 0xFFFFFu) * 32 + l32];
          const uint2 rA = rf2[(size_t)(pkA >> 20) * 32 + l32];
          const uint2 avB = xb2[(size_t)(pkB & 0xFFFFFu) * 32 + l32];
          const uint2 rB = rf2[(size_t)(pkB >> 20) * 32 + l32];
          a0 += wA * (bflo(avA.x) - bflo(rA.x));
          a1 += wA * (bfhi(avA.x) - bfhi(rA.x));
          a2 += wA * (bflo(avA.y) - bflo(rA.y));
          a3 += wA * (bfhi(avA.y) - bfhi(rA.y));
          a0 += wB * (bflo(avB.x) - bflo(rB.x));
          a1 += wB * (bfhi(avB.x) - bfhi(rB.x));
          a2 += wB * (bflo(avB.y) - bflo(rB.y));
          a3 += wB * (bfhi(avB.y) - bfhi(rB.y));
        }
        if (jb < m) {
          const unsigned pk = (unsigned)__shfl((int)mv.x, jb, 32);
          const float wv = __uint_as_float(__shfl((int)mv.y, jb, 32));
          const uint2 av = xb2[(size_t)(pk & 0xFFFFFu) * 32 + l32];
          const uint2 rv = rf2[(size_t)(pk >> 20) * 32 + l32];
          a0 += wv * (bflo(av.x) - bflo(rv.x));
          a1 += wv * (bfhi(av.x) - bfhi(rv.x));
          a2 += wv * (bflo(av.y) - bflo(rv.y));
          a3 += wv * (bfhi(av.y) - bfhi(rv.y));
        }
      }
      *(float4*)&hsm[nl][l32 * 4] = make_float4(a0, a1, a2, a3);
    }
  } else {
    for (int idx = tid; idx < NT * 32; idx += 256) {
      const int rr = idx >> 5, cc = (idx & 31) * 4;
      const int n = g0 + rr;
      float4 v = make_float4(0.f, 0.f, 0.f, 0.f);
      if (n < nN && hg) v = *(const float4*)(hg + (size_t)n * D + cc);
      *(float4*)&hsm[rr][cc] = v;
    }
  }
  __syncthreads();

  // ---- GEMM phase: wave w = (row-half w>>1, col-half w&1) -------------
  const int w = tid >> 6, lane = tid & 63;
  const int q = lane >> 4, r = lane & 15;
  const int rowbase = (w >> 1) * 16;
  const int ch = w & 1;
  const int lr = rowbase + r;
  int grow = g0 + lr; if (grow >= nN) grow = nN - 1;

  f32x4 acc[4];
  #pragma unroll
  for (int c2 = 0; c2 < 4; ++c2) acc[c2] = (f32x4)0.f;

  #pragma unroll
  for (int kt = 0; kt < 4; ++kt) {
    const bf16x8 xa = *(const bf16x8*)(xb + (size_t)grow * D + kt * 32 + q * 8);
    const float* hp = &hsm[lr][kt * 32 + q * 8];
    const float4 h0 = *(const float4*)hp;
    const float4 h1 = *(const float4*)(hp + 4);
    const float hv[8] = {h0.x, h0.y, h0.z, h0.w, h1.x, h1.y, h1.z, h1.w};
    bf16x8 hi, lo;
    #pragma unroll
    for (int j = 0; j < 8; ++j) {
      const unsigned short hb = f2bf(hv[j]);
      hi[j] = (short)hb;
      lo[j] = (short)f2bf(hv[j] - bf2f(hb));
    }
    #pragma unroll
    for (int c2 = 0; c2 < 4; ++c2) {
      const int ct = ch * 4 + c2;
      const bf16x8 bS = *(const bf16x8*)(Wb + ((0 * 8 + ct) * 4 + kt) * 512 + lane * 8);
      const bf16x8 bF = *(const bf16x8*)(Wb + ((1 * 8 + ct) * 4 + kt) * 512 + lane * 8);
      acc[c2] = __builtin_amdgcn_mfma_f32_16x16x32_bf16(xa, bS, acc[c2], 0, 0, 0);
      acc[c2] = __builtin_amdgcn_mfma_f32_16x16x32_bf16(hi, bF, acc[c2], 0, 0, 0);
      acc[c2] = __builtin_amdgcn_mfma_f32_16x16x32_bf16(lo, bF, acc[c2], 0, 0, 0);
    }
  }

  #pragma unroll
  for (int c2 = 0; c2 < 4; ++c2) {
    const int col = ch * 64 + c2 * 16 + r;
    const float bv = bias[col];
    #pragma unroll
    for (int reg = 0; reg < 4; ++reg) {
      const int row = g0 + rowbase + q * 4 + reg;
      if (row < nN) out[(size_t)row * D + col] = acc[c2][reg] + bv;
    }
  }
}

// ---------------------------------------------------------------------------
// Fallbacks (never taken at harness sizes)
// ---------------------------------------------------------------------------
__global__ __launch_bounds__(256) void hzero(float* __restrict__ h, int n4) {
  const int i = blockIdx.x * 256 + threadIdx.x;
  if (i < n4) ((int4*)h)[i] = make_int4(0, 0, 0, 0);
}

__global__ __launch_bounds__(256) void hscatter(
    const uint4* __restrict__ xb4, const float* __restrict__ rel,
    const int* __restrict__ ei, const int* __restrict__ etype,
    const float* __restrict__ ew, float* __restrict__ h, int nE) {
  const int e = blockIdx.x * 16 + ((int)threadIdx.x >> 4);
  if (e >= nE) return;
  const int l = threadIdx.x & 15;
  const int s = ei[e], d = ei[nE + e], t = etype[e];
  const float wv = ew[e];
  const uint4 a = xb4[(size_t)s * 16 + l];
  const float4 r0 = ((const float4*)(rel + (size_t)t * D))[l * 2];
  const float4 r1 = ((const float4*)(rel + (size_t)t * D))[l * 2 + 1];
  float* o = h + (size_t)d * D + l * 8;
  atomicAdd(o + 0, wv * (bflo(a.x) - r0.x));
  atomicAdd(o + 1, wv * (bfhi(a.x) - r0.y));
  atomicAdd(o + 2, wv * (bflo(a.y) - r0.z));
  atomicAdd(o + 3, wv * (bfhi(a.y) - r0.w));
  atomicAdd(o + 4, wv * (bflo(a.z) - r1.x));
  atomicAdd(o + 5, wv * (bfhi(a.z) - r1.y));
  atomicAdd(o + 6, wv * (bflo(a.w) - r1.z));
  atomicAdd(o + 7, wv * (bfhi(a.w) - r1.w));
}

__global__ __launch_bounds__(256) void edge_scatter_f32(
    const float* __restrict__ x, const float* __restrict__ rel,
    const float* __restrict__ Wfwd,
    const int* __restrict__ ei, const int* __restrict__ etype,
    const float* __restrict__ ew, float* __restrict__ out, int nE) {
  __shared__ float msg[2][D];
  const int half = (int)threadIdx.x >> 7;
  const int c = threadIdx.x & 127;
  const int e = blockIdx.x * 2 + half;
  if (e >= nE) return;
  const int s = ei[e], d = ei[nE + e], t = etype[e];
  msg[half][c] = x[(size_t)s * D + c] - rel[(size_t)t * D + c];
  __syncthreads();
  float a = 0.f;
  #pragma unroll 8
  for (int k = 0; k < D; ++k) a += msg[half][k] * Wfwd[c * D + k];
  atomicAdd(&out[(size_t)d * D + c], ew[e] * a);
}

// ---------------------------------------------------------------------------
extern "C" void kernel_launch(void* const* d_in, const int* in_sizes, int n_in,
                              void* d_out, int out_size, void* d_ws, size_t ws_size,
                              hipStream_t stream) {
  const float* x      = (const float*)d_in[0];
  const int*   ei     = (const int*)d_in[1];
  const int*   etype  = (const int*)d_in[2];
  const float* rel    = (const float*)d_in[3];
  const float* ew     = (const float*)d_in[4];
  const float* Wself  = (const float*)d_in[5];
  const float* Wfwd   = (const float*)d_in[6];
  const float* Wrel   = (const float*)d_in[7];
  const float* bias   = (const float*)d_in[8];

  const int nN = in_sizes[0] / D;       // 100000
  const int nE = in_sizes[2];           // 625000
  const int nR = in_sizes[3] / D;       // 200

  float* out     = (float*)d_out;
  float* rel_out = (float*)d_out + (size_t)nN * D;

  // workspace carve-up (256B-aligned). offs and bsum adjacent => ONE memset.
  char* w = (char*)d_ws;
  size_t off = 0;
  auto carve = [&](size_t bytes) {
    char* p = w + off;
    off = (off + bytes + 255) & ~(size_t)255;
    return p;
  };
  unsigned short* xb  = (unsigned short*)carve((size_t)nN * D * sizeof(unsigned short));
  unsigned short* rfb = (unsigned short*)carve((size_t)nR * D * sizeof(unsigned short));
  unsigned short* Wb  = (unsigned short*)carve(2 * 8 * 4 * 512 * sizeof(unsigned short));
  int*   offs = (int*)carve((size_t)nN * sizeof(int));
  int*   bsum = (int*)carve(4096 * sizeof(int));
  uint2* meta = (uint2*)carve((size_t)nE * sizeof(uint2));
  const size_t need = off;
  const size_t zeroSpan = (size_t)((char*)(bsum + 4096) - (char*)offs);

  const int* dst = ei + nE;
  const int nb = (nN + SCAN_B - 1) / SCAN_B;
  const int relBlocks  = (nR + 1) / 2;
  const int rfbBlocks  = (int)(((size_t)nR * D + 2047) / 2048);
  const int xbBlocks   = (int)(((size_t)nN * D + 2047) / 2048);
  const int histBlocks = (nE + 1023) / 1024;
  const int aggBlocks  = (nN + NT - 1) / NT;

  const bool csr_ok = (need <= ws_size) && (nb <= 4096) &&
                      (nN < (1 << 20)) && (nR <= 4096);
  const bool fast_scan = (nb <= 512) && (nE < (1 << 30));
  const size_t hBytes = (size_t)nN * D * sizeof(float);
  const bool h_ok = ((size_t)nN * D * sizeof(unsigned short) + 256 + hBytes) <= ws_size;

  if (csr_ok) {
    // D0: zero offs+bsum via SDMA (stream-ordered, graph-capture safe)
    (void)hipMemsetAsync(offs, 0, zeroSpan, stream);
    // K1: Wb + rel_out + rfb + xb + histogram
    prep_xb_hist<<<16 + relBlocks + rfbBlocks + xbBlocks + histBlocks, 256, 0, stream>>>(
        Wself, Wfwd, rel, Wrel, x, xb, rfb, Wb, rel_out, dst, offs,
        nR, nN, nE, relBlocks, rfbBlocks, xbBlocks);
    // K2: exclusive scan
    if (fast_scan) {
      scan_single<<<nb, 256, 0, stream>>>(offs, bsum, nN);
    } else {
      scan_pass1<<<nb, SCAN_B, 0, stream>>>(offs, bsum, nN);
      scan_pass3<<<nb, SCAN_B, 0, stream>>>(offs, bsum, nN);
    }
    // K3: CSR fill
    fill_kernel<<<(nE + 255) / 256, 256, 0, stream>>>(ei, dst, etype, ew, offs, meta, nE);
    // K4: fused aggregate + GEMM
    fused_ag<<<aggBlocks, 256, 0, stream>>>(
        xb, rfb, meta, offs, Wb, bias, out, nN, 0, (const float*)0);
  } else if (h_ok) {
    prep_xb_hist<<<16 + relBlocks + rfbBlocks + xbBlocks, 256, 0, stream>>>(
        Wself, Wfwd, rel, Wrel, x, xb, rfb, Wb, rel_out, dst, (int*)0,
        nR, nN, 0, relBlocks, rfbBlocks, xbBlocks);
    float* h = (float*)(w + (((size_t)nN * D * sizeof(unsigned short) + 255) & ~(size_t)255));
    const int n4 = (nN * D) / 4;
    hzero<<<(n4 + 255) / 256, 256, 0, stream>>>(h, n4);
    hscatter<<<(nE + 15) / 16, 256, 0, stream>>>(
        (const uint4*)xb, rel, ei, etype, ew, h, nE);
    fused_ag<<<aggBlocks, 256, 0, stream>>>(
        xb, rfb, (const uint2*)0, (const int*)0, Wb, bias, out, nN, 1, h);
  } else {
    prep_xb_hist<<<16 + relBlocks + rfbBlocks + xbBlocks, 256, 0, stream>>>(
        Wself, Wfwd, rel, Wrel, x, xb, rfb, Wb, rel_out, dst, (int*)0,
        nR, nN, 0, relBlocks, rfbBlocks, xbBlocks);
    fused_ag<<<aggBlocks, 256, 0, stream>>>(
        xb, rfb, (const uint2*)0, (const int*)0, Wb, bias, out, nN, 1,
        (const float*)0);
    edge_scatter_f32<<<(nE + 1) / 2, 256, 0, stream>>>(
        x, rel, Wfwd, ei, etype, ew, out, nE);
  }
}